// Round 1
// baseline (730.688 us; speedup 1.0000x reference)
//
#include <hip/hip_runtime.h>
#include <hip/hip_bf16.h>

#define DEV static __device__ __forceinline__

typedef float f32x4 __attribute__((ext_vector_type(4)));
typedef __bf16 b16x8 __attribute__((ext_vector_type(8)));

DEV unsigned short f2bf(float f) {
  union { __hip_bfloat16 h; unsigned short u; } cv;
  cv.h = __float2bfloat16(f);
  return cv.u;
}

DEV void gload_lds16(const unsigned short* g, unsigned short* l) {
  __builtin_amdgcn_global_load_lds(
      (__attribute__((address_space(1))) void*)g,
      (__attribute__((address_space(3))) void*)l, 16, 0, 0);
}

// ---------------- f32 -> bf16 elementwise ----------------
__global__ __launch_bounds__(256) void k_conv_bf16(const float* __restrict__ src,
                                                   unsigned short* __restrict__ dst,
                                                   long long n4) {
  long long i = (long long)blockIdx.x * 256 + threadIdx.x;
  if (i >= n4) return;
  const float4 v = ((const float4*)src)[i];
  ushort4 o;
  o.x = f2bf(v.x); o.y = f2bf(v.y); o.z = f2bf(v.z); o.w = f2bf(v.w);
  ((ushort4*)dst)[i] = o;
}

// ---------------- f32 [z][R][C] -> bf16 [z][C][R] ----------------
__global__ __launch_bounds__(256) void k_transpose_bf16(const float* __restrict__ src,
                                                        unsigned short* __restrict__ dst,
                                                        int R, int C) {
  __shared__ float t[32][33];
  const long long zo = (long long)blockIdx.z * R * C;
  const int c0 = blockIdx.x * 32, r0 = blockIdx.y * 32;
  const int tx = threadIdx.x, ty = threadIdx.y;
#pragma unroll
  for (int i = 0; i < 4; ++i)
    t[ty + i * 8][tx] = src[zo + (long long)(r0 + ty + i * 8) * C + c0 + tx];
  __syncthreads();
#pragma unroll
  for (int i = 0; i < 4; ++i)
    dst[zo + (long long)(c0 + ty + i * 8) * R + r0 + tx] = f2bf(t[tx][ty + i * 8]);
}

// ---------------- row softmax over 1024 f32 -> bf16, one wave per row ----------------
__global__ __launch_bounds__(256) void k_softmax1024(const float* __restrict__ S,
                                                     unsigned short* __restrict__ P) {
  const int wave = threadIdx.x >> 6, lane = threadIdx.x & 63;
  const long long row = (long long)blockIdx.x * 4 + wave;
  const float4* src = (const float4*)(S + row * 1024);
  float4 v[4];
  float mx = -3.0e38f;
#pragma unroll
  for (int i = 0; i < 4; ++i) {
    v[i] = src[i * 64 + lane];
    mx = fmaxf(mx, fmaxf(fmaxf(v[i].x, v[i].y), fmaxf(v[i].z, v[i].w)));
  }
#pragma unroll
  for (int off = 32; off > 0; off >>= 1) mx = fmaxf(mx, __shfl_xor(mx, off));
  float sum = 0.f;
#pragma unroll
  for (int i = 0; i < 4; ++i) {
    v[i].x = __expf(v[i].x - mx); v[i].y = __expf(v[i].y - mx);
    v[i].z = __expf(v[i].z - mx); v[i].w = __expf(v[i].w - mx);
    sum += v[i].x + v[i].y + v[i].z + v[i].w;
  }
#pragma unroll
  for (int off = 32; off > 0; off >>= 1) sum += __shfl_xor(sum, off);
  const float inv = 1.f / sum;
  unsigned short* dst = P + row * 1024;
#pragma unroll
  for (int i = 0; i < 4; ++i) {
    ushort4 o;
    o.x = f2bf(v[i].x * inv); o.y = f2bf(v[i].y * inv);
    o.z = f2bf(v[i].z * inv); o.w = f2bf(v[i].w * inv);
    *(ushort4*)(dst + (i * 64 + lane) * 4) = o;
  }
}

// ---------------- bf16 GEMM: C[M,N] = A[M,K] * Bt[N,K]^T  (m97 structure) ----------------
// A-frag: lane reads A[m0+(l&15)][k0+(l>>4)*8+j]; Bt-frag identical addressing.
// C/D layout (verified): col = lane&15, row = (lane>>4)*4 + reg.
// Offsets per z: A += (z>>azs)*azr; Bt += (z&7)*bzr; C += z*czr + (z&czm)*czc;
// bias[(z&biasm)*bstr + col] added; val = acc*scale + bias.
template <bool BF16OUT, bool TRANS>
__global__ __launch_bounds__(256) void k_gemm_bt(
    const unsigned short* __restrict__ A, const unsigned short* __restrict__ Bt,
    void* __restrict__ Cv, const float* __restrict__ bias,
    int K, int lda, int ldb, int ldc,
    int azs, long long azr, long long bzr,
    long long czr, int czm, int czc, int biasm, int bstr, float scale) {
  __shared__ unsigned short lA[128 * 64];
  __shared__ unsigned short lB[128 * 64];
  const int tid = threadIdx.x, wave = tid >> 6, lane = tid & 63;
  const int z = blockIdx.z;
  const int m0 = blockIdx.y * 128, n0 = blockIdx.x * 128;
  const unsigned short* Az = A + (long long)(z >> azs) * azr + (long long)m0 * lda;
  const unsigned short* Bz = Bt + (long long)(z & 7) * bzr + (long long)n0 * ldb;

  // staging: each wave stages 32 rows of each tile; one inst = 8 rows (64 lanes x 8 bf16)
  const int srow = wave * 32 + (lane >> 3);
  const int scol = (lane & 7) * 8;
  const unsigned short* ga = Az + (long long)srow * lda + scol;
  const unsigned short* gb = Bz + (long long)srow * ldb + scol;
  unsigned short* laBase = &lA[(wave * 32) * 64];
  unsigned short* lbBase = &lB[(wave * 32) * 64];

  f32x4 acc[4][4] = {};
  const int wr = (wave >> 1) * 64, wc = (wave & 1) * 64;
  const int fr = lane & 15, kq = (lane >> 4) * 8;

  for (int k0 = 0; k0 < K; k0 += 64) {
#pragma unroll
    for (int i = 0; i < 4; ++i) {
      gload_lds16(ga + (long long)(i * 8) * lda + k0, laBase + (i * 8) * 64);
      gload_lds16(gb + (long long)(i * 8) * ldb + k0, lbBase + (i * 8) * 64);
    }
    __syncthreads();
#pragma unroll
    for (int kk = 0; kk < 64; kk += 32) {
      b16x8 af[4], bf[4];
#pragma unroll
      for (int i = 0; i < 4; ++i)
        af[i] = *(const b16x8*)&lA[(wr + i * 16 + fr) * 64 + kk + kq];
#pragma unroll
      for (int j = 0; j < 4; ++j)
        bf[j] = *(const b16x8*)&lB[(wc + j * 16 + fr) * 64 + kk + kq];
#pragma unroll
      for (int i = 0; i < 4; ++i)
#pragma unroll
        for (int j = 0; j < 4; ++j)
          acc[i][j] = __builtin_amdgcn_mfma_f32_16x16x32_bf16(af[i], bf[j], acc[i][j], 0, 0, 0);
    }
    __syncthreads();
  }

  const long long coff = (long long)z * czr + (long long)(z & czm) * czc;
  const int rr = (lane >> 4) * 4;
#pragma unroll
  for (int j = 0; j < 4; ++j) {
    const int col = n0 + wc + j * 16 + fr;
    const float bval = bias ? bias[(long long)(z & biasm) * bstr + col] : 0.f;
#pragma unroll
    for (int i = 0; i < 4; ++i) {
#pragma unroll
      for (int r = 0; r < 4; ++r) {
        const int row = m0 + wr + i * 16 + rr + r;
        const float val = acc[i][j][r] * scale + bval;
        if constexpr (BF16OUT) {
          unsigned short* Cb = (unsigned short*)Cv;
          if constexpr (TRANS)
            Cb[coff + (long long)col * ldc + row] = f2bf(val);
          else
            Cb[coff + (long long)row * ldc + col] = f2bf(val);
        } else {
          ((float*)Cv)[coff + (long long)row * ldc + col] = val;
        }
      }
    }
  }
}

extern "C" void kernel_launch(void* const* d_in, const int* in_sizes, int n_in,
                              void* d_out, int out_size, void* d_ws, size_t ws_size,
                              hipStream_t stream) {
  const float* in1 = (const float*)d_in[0];
  const float* in2 = (const float*)d_in[1];
  const float* in3 = (const float*)d_in[2];
  const float* Wq = (const float*)d_in[3];
  const float* bq = (const float*)d_in[4];
  const float* Wk = (const float*)d_in[5];
  const float* bk = (const float*)d_in[6];
  const float* Wv = (const float*)d_in[7];
  const float* bv = (const float*)d_in[8];
  const float* Wo = (const float*)d_in[9];
  const float* bo = (const float*)d_in[10];

  const long long B = 8, S = 1024, D = 512, E = 512, H = 8;
  const long long SZ_IN = B * S * D * 2;       // one bf16 input: 8 MiB
  const long long SZ_W = H * D * E * 2;        // one bf16 weight set: 4 MiB
  const long long SZ_QKV = B * H * S * E * 2;  // 64 MiB
  const long long SZ_P = H * S * S * 2;        // per-b P: 16 MiB

  unsigned char* w = (unsigned char*)d_ws;
  unsigned short* in1b = (unsigned short*)(w);
  unsigned short* in2b = (unsigned short*)(w + SZ_IN);
  unsigned short* in3b = (unsigned short*)(w + 2 * SZ_IN);
  unsigned short* wqt = (unsigned short*)(w + 3 * SZ_IN);
  unsigned short* wkt = (unsigned short*)(w + 3 * SZ_IN + SZ_W);
  float* scores = (float*)w;  // aliases [in1b..wkt], dead after projections
  unsigned char* base2 = w + 3 * SZ_IN + 2 * SZ_W;
  unsigned short* wvt = (unsigned short*)(base2);
  unsigned short* wot = (unsigned short*)(base2 + SZ_W);
  unsigned short* Q = (unsigned short*)(base2 + 2 * SZ_W);
  unsigned short* KC = (unsigned short*)(base2 + 2 * SZ_W + SZ_QKV);      // K, then concat (slab b dead after scores(b))
  unsigned short* Vt = (unsigned short*)(base2 + 2 * SZ_W + 2 * SZ_QKV);  // V transposed [z][E][S]
  unsigned short* P = (unsigned short*)(base2 + 2 * SZ_W + 3 * SZ_QKV);
  const long long need = 3 * SZ_IN + 2 * SZ_W + 2 * SZ_W + 3 * SZ_QKV + SZ_P;
  if ((long long)ws_size < need) return;

  const float iscale = 0.04419417382415922f;  // 1/sqrt(512)

  // dtype conversions / weight transposes
  k_conv_bf16<<<4096, 256, 0, stream>>>(in1, in1b, (B * S * D) / 4);
  k_conv_bf16<<<4096, 256, 0, stream>>>(in2, in2b, (B * S * D) / 4);
  k_conv_bf16<<<4096, 256, 0, stream>>>(in3, in3b, (B * S * D) / 4);
  k_transpose_bf16<<<dim3(16, 16, 8), dim3(32, 8), 0, stream>>>(Wq, wqt, 512, 512);
  k_transpose_bf16<<<dim3(16, 16, 8), dim3(32, 8), 0, stream>>>(Wk, wkt, 512, 512);
  k_transpose_bf16<<<dim3(16, 16, 8), dim3(32, 8), 0, stream>>>(Wv, wvt, 512, 512);
  k_transpose_bf16<<<dim3(16, 128, 1), dim3(32, 8), 0, stream>>>(Wo, wot, 4096, 512);

  // projections: z = b*8+h; A by b, Bt/bias by h, C by z
  k_gemm_bt<true, false><<<dim3(4, 8, 64), 256, 0, stream>>>(
      in1b, wqt, Q, bq, 512, 512, 512, 512, 3, S * D, (long long)E * D,
      S * E, 0, 0, 7, 512, 1.0f);
  k_gemm_bt<true, false><<<dim3(4, 8, 64), 256, 0, stream>>>(
      in2b, wkt, KC, bk, 512, 512, 512, 512, 3, S * D, (long long)E * D,
      S * E, 0, 0, 7, 512, 1.0f);
  k_gemm_bt<true, true><<<dim3(4, 8, 64), 256, 0, stream>>>(
      in3b, wvt, Vt, bv, 512, 512, 512, 1024, 3, S * D, (long long)E * D,
      (long long)E * S, 0, 0, 7, 512, 1.0f);

  // attention, chunked by batch b (stream-ordered, scores/P buffers reused)
  for (int b = 0; b < 8; ++b) {
    const unsigned short* Qb = Q + (long long)b * H * S * E;
    const unsigned short* Kb = KC + (long long)b * H * S * E;
    const unsigned short* Vb = Vt + (long long)b * H * E * S;
    unsigned short* Cb = KC + (long long)b * S * (H * E);  // concat slab b (aliases K slab b, now dead)
    // scores[h][q][k] = (Q K^T) * 1/sqrt(512), f32
    k_gemm_bt<false, false><<<dim3(8, 8, 8), 256, 0, stream>>>(
        Qb, Kb, scores, nullptr, 512, 512, 512, 1024, 0, S * E, S * E,
        (long long)S * S, 0, 0, 0, 0, iscale);
    k_softmax1024<<<2048, 256, 0, stream>>>(scores, P);
    // heads = P @ V -> concat[b*S + s][h*512 + e] bf16
    k_gemm_bt<true, false><<<dim3(4, 8, 8), 256, 0, stream>>>(
        P, Vb, Cb, nullptr, 1024, 1024, 1024, 4096, 0, (long long)S * S,
        (long long)E * S, 0, 7, 512, 0, 0, 1.0f);
  }

  // out = concat[8192,4096] @ Wo^T(wot[512,4096]) + bo, f32
  k_gemm_bt<false, false><<<dim3(4, 64, 1), 256, 0, stream>>>(
      KC, wot, d_out, bo, 4096, 4096, 4096, 512, 0, 0, 0,
      0, 0, 0, 0, 0, 1.0f);
}

// Round 2
// 708.571 us; speedup vs baseline: 1.0312x; 1.0312x over previous
//
#include <hip/hip_runtime.h>
#include <hip/hip_bf16.h>

#define DEV static __device__ __forceinline__

typedef float f32x4 __attribute__((ext_vector_type(4)));
typedef __bf16 b16x8 __attribute__((ext_vector_type(8)));

DEV unsigned short f2bf(float f) {
  union { __hip_bfloat16 h; unsigned short u; } cv;
  cv.h = __float2bfloat16(f);
  return cv.u;
}

DEV void gload_lds16(const unsigned short* g, unsigned short* l) {
  __builtin_amdgcn_global_load_lds(
      (__attribute__((address_space(1))) void*)g,
      (__attribute__((address_space(3))) void*)l, 16, 0, 0);
}

// ---------------- f32 -> bf16 elementwise ----------------
__global__ __launch_bounds__(256) void k_conv_bf16(const float* __restrict__ src,
                                                   unsigned short* __restrict__ dst,
                                                   long long n4) {
  long long i = (long long)blockIdx.x * 256 + threadIdx.x;
  if (i >= n4) return;
  const float4 v = ((const float4*)src)[i];
  ushort4 o;
  o.x = f2bf(v.x); o.y = f2bf(v.y); o.z = f2bf(v.z); o.w = f2bf(v.w);
  ((ushort4*)dst)[i] = o;
}

// ---------------- f32 [z][R][C] -> bf16 [z][C][R] ----------------
__global__ __launch_bounds__(256) void k_transpose_bf16(const float* __restrict__ src,
                                                        unsigned short* __restrict__ dst,
                                                        int R, int C) {
  __shared__ float t[32][33];
  const long long zo = (long long)blockIdx.z * R * C;
  const int c0 = blockIdx.x * 32, r0 = blockIdx.y * 32;
  const int tx = threadIdx.x, ty = threadIdx.y;
#pragma unroll
  for (int i = 0; i < 4; ++i)
    t[ty + i * 8][tx] = src[zo + (long long)(r0 + ty + i * 8) * C + c0 + tx];
  __syncthreads();
#pragma unroll
  for (int i = 0; i < 4; ++i)
    dst[zo + (long long)(c0 + ty + i * 8) * R + r0 + tx] = f2bf(t[tx][ty + i * 8]);
}

// ---------------- u[h,d]=sum_e Wq[h,d,e]*bk[h,e] (sel0) / v from Wk,bq (sel1) ----------------
__global__ __launch_bounds__(256) void k_uv(const float* __restrict__ Wq, const float* __restrict__ bk,
                                            const float* __restrict__ Wk, const float* __restrict__ bq,
                                            float* __restrict__ u, float* __restrict__ v) {
  const int sel = blockIdx.y;
  const float* W = sel ? Wk : Wq;
  const float* bb = sel ? bq : bk;
  float* dst = sel ? v : u;
  const int wave = threadIdx.x >> 6, lane = threadIdx.x & 63;
  const int idx = blockIdx.x * 4 + wave;  // flat (h,d): h=idx>>9, d=idx&511
  const int h = idx >> 9, d = idx & 511;
  const float* wr = W + ((long long)h * 512 + d) * 512 + lane * 8;
  const float* br = bb + h * 512 + lane * 8;
  float s = 0.f;
#pragma unroll
  for (int k = 0; k < 8; ++k) s += wr[k] * br[k];
#pragma unroll
  for (int off = 32; off; off >>= 1) s += __shfl_xor(s, off);
  if (lane == 0) dst[h * 512 + d] = s;
}

// ---------------- c[h] = bq[h].bk[h] ----------------
__global__ __launch_bounds__(512) void k_bdot(const float* __restrict__ bq,
                                              const float* __restrict__ bk,
                                              float* __restrict__ c) {
  const int wave = threadIdx.x >> 6, lane = threadIdx.x & 63;
  const float* a = bq + wave * 512 + lane * 8;
  const float* b = bk + wave * 512 + lane * 8;
  float s = 0.f;
#pragma unroll
  for (int k = 0; k < 8; ++k) s += a[k] * b[k];
#pragma unroll
  for (int off = 32; off; off >>= 1) s += __shfl_xor(s, off);
  if (lane == 0) c[wave] = s;
}

// ---------------- rt[b*8+h][i] = in1[b,i,:].u[h,:] + c[h]  (sel0) ; ct from in2,v (sel1) ----------------
__global__ __launch_bounds__(256) void k_rtct(const float* __restrict__ in1, const float* __restrict__ in2,
                                              const float* __restrict__ u, const float* __restrict__ v,
                                              const float* __restrict__ cbuf,
                                              float* __restrict__ rt, float* __restrict__ ct) {
  const int sel = blockIdx.y;
  const float* src = sel ? in2 : in1;
  const float* vec = sel ? v : u;
  float* dst = sel ? ct : rt;
  const int row = blockIdx.x;  // 0..8191: b=row>>10, i=row&1023
  __shared__ float x[512];
  const float* p = src + (long long)row * 512;
  x[threadIdx.x] = p[threadIdx.x];
  x[threadIdx.x + 256] = p[threadIdx.x + 256];
  __syncthreads();
  const int wave = threadIdx.x >> 6, lane = threadIdx.x & 63;
  const int b = row >> 10, i = row & 1023;
#pragma unroll
  for (int t = 0; t < 2; ++t) {
    const int h = wave * 2 + t;
    const float* wv = vec + h * 512;
    float s = 0.f;
#pragma unroll
    for (int k = 0; k < 8; ++k) s += x[lane + k * 64] * wv[lane + k * 64];
#pragma unroll
    for (int off = 32; off; off >>= 1) s += __shfl_xor(s, off);
    if (lane == 0)
      dst[((long long)(b * 8 + h)) * 1024 + i] = s + (sel ? 0.f : cbuf[h]);
  }
}

// ---------------- in-place row softmax over 1024 bf16, one wave per row ----------------
__global__ __launch_bounds__(256) void k_softmax_bf16(unsigned short* __restrict__ P) {
  const int wave = threadIdx.x >> 6, lane = threadIdx.x & 63;
  unsigned short* p = P + ((long long)blockIdx.x * 4 + wave) * 1024 + lane * 16;
  const b16x8 v0 = *(const b16x8*)p;
  const b16x8 v1 = *(const b16x8*)(p + 8);
  float f[16];
#pragma unroll
  for (int j = 0; j < 8; ++j) { f[j] = (float)v0[j]; f[8 + j] = (float)v1[j]; }
  float mx = f[0];
#pragma unroll
  for (int j = 1; j < 16; ++j) mx = fmaxf(mx, f[j]);
#pragma unroll
  for (int off = 32; off; off >>= 1) mx = fmaxf(mx, __shfl_xor(mx, off));
  float sum = 0.f;
#pragma unroll
  for (int j = 0; j < 16; ++j) { f[j] = __expf(f[j] - mx); sum += f[j]; }
#pragma unroll
  for (int off = 32; off; off >>= 1) sum += __shfl_xor(sum, off);
  const float inv = 1.f / sum;
  b16x8 o0, o1;
#pragma unroll
  for (int j = 0; j < 8; ++j) { o0[j] = (__bf16)(f[j] * inv); o1[j] = (__bf16)(f[8 + j] * inv); }
  *(b16x8*)p = o0;
  *(b16x8*)(p + 8) = o1;
}

// ---------------- bf16 GEMM: C[M,N] = A[M,K] * Bt[N,K]^T  (m97 structure) ----------------
// OM: 0=f32 out, 1=bf16 out, 2=bf16 transposed out.
// Az = A + ((z>>azs)&azm)*azr + m0*lda ; Bz = Bt + ((z>>bzs)&bzm)*bzr + n0*ldb
// coff = (z>>czs)*czr + (z&czm)*czc
// val = (acc + rAdd[z*rstr+row] + cAdd[z*rstr+col]) * scale + bias[(z&biasm)*bstr + col]
template <int OM>
__global__ __launch_bounds__(256) void k_gemm_bt(
    const unsigned short* __restrict__ A, const unsigned short* __restrict__ Bt,
    void* __restrict__ Cv, const float* __restrict__ bias,
    const float* __restrict__ rAdd, const float* __restrict__ cAdd,
    int K, int lda, int ldb, int ldc,
    int azs, int azm, long long azr,
    int bzs, int bzm, long long bzr,
    int czs, long long czr, int czm, int czc,
    int biasm, int bstr, int rstr, float scale) {
  __shared__ unsigned short lA[128 * 64];
  __shared__ unsigned short lB[128 * 64];
  const int tid = threadIdx.x, wave = tid >> 6, lane = tid & 63;
  const int z = blockIdx.z;
  const int m0 = blockIdx.y * 128, n0 = blockIdx.x * 128;
  const unsigned short* Az = A + (long long)((z >> azs) & azm) * azr + (long long)m0 * lda;
  const unsigned short* Bz = Bt + (long long)((z >> bzs) & bzm) * bzr + (long long)n0 * ldb;

  const int srow = wave * 32 + (lane >> 3);
  const int scol = (lane & 7) * 8;
  const unsigned short* ga = Az + (long long)srow * lda + scol;
  const unsigned short* gb = Bz + (long long)srow * ldb + scol;
  unsigned short* laBase = &lA[(wave * 32) * 64];
  unsigned short* lbBase = &lB[(wave * 32) * 64];

  f32x4 acc[4][4] = {};
  const int wr = (wave >> 1) * 64, wc = (wave & 1) * 64;
  const int fr = lane & 15, kq = (lane >> 4) * 8;

  for (int k0 = 0; k0 < K; k0 += 64) {
#pragma unroll
    for (int i = 0; i < 4; ++i) {
      gload_lds16(ga + (long long)(i * 8) * lda + k0, laBase + (i * 8) * 64);
      gload_lds16(gb + (long long)(i * 8) * ldb + k0, lbBase + (i * 8) * 64);
    }
    __syncthreads();
#pragma unroll
    for (int kk = 0; kk < 64; kk += 32) {
      b16x8 af[4], bf[4];
#pragma unroll
      for (int i = 0; i < 4; ++i)
        af[i] = *(const b16x8*)&lA[(wr + i * 16 + fr) * 64 + kk + kq];
#pragma unroll
      for (int j = 0; j < 4; ++j)
        bf[j] = *(const b16x8*)&lB[(wc + j * 16 + fr) * 64 + kk + kq];
#pragma unroll
      for (int i = 0; i < 4; ++i)
#pragma unroll
        for (int j = 0; j < 4; ++j)
          acc[i][j] = __builtin_amdgcn_mfma_f32_16x16x32_bf16(af[i], bf[j], acc[i][j], 0, 0, 0);
    }
    __syncthreads();
  }

  const long long coff = (long long)(z >> czs) * czr + (long long)(z & czm) * czc;
  const long long zr = (long long)z * rstr;
  const int rr = (lane >> 4) * 4;
#pragma unroll
  for (int j = 0; j < 4; ++j) {
    const int col = n0 + wc + j * 16 + fr;
    const float bval = bias ? bias[(long long)(z & biasm) * bstr + col] : 0.f;
    const float ca = cAdd ? cAdd[zr + col] : 0.f;
#pragma unroll
    for (int i = 0; i < 4; ++i) {
#pragma unroll
      for (int r = 0; r < 4; ++r) {
        const int row = m0 + wr + i * 16 + rr + r;
        const float ra = rAdd ? rAdd[zr + row] : 0.f;
        const float val = (acc[i][j][r] + ra + ca) * scale + bval;
        if constexpr (OM == 1) {
          ((unsigned short*)Cv)[coff + (long long)row * ldc + col] = f2bf(val);
        } else if constexpr (OM == 2) {
          ((unsigned short*)Cv)[coff + (long long)col * ldc + row] = f2bf(val);
        } else {
          ((float*)Cv)[coff + (long long)row * ldc + col] = val;
        }
      }
    }
  }
}

// ---------------- out = sum of 4 f32 partials + bias(per 512 cols) ----------------
__global__ __launch_bounds__(256) void k_reduce4(const float* __restrict__ p,
                                                 const float* __restrict__ bo,
                                                 float* __restrict__ out) {
  const long long i = (long long)blockIdx.x * 256 + threadIdx.x;  // float4 idx, 1048576 total
  const float4* p4 = (const float4*)p;
  float4 a = p4[i], b = p4[i + 1048576], c = p4[i + 2097152], d = p4[i + 3145728];
  const float4 bb = ((const float4*)bo)[i & 127];
  float4 o;
  o.x = a.x + b.x + c.x + d.x + bb.x;
  o.y = a.y + b.y + c.y + d.y + bb.y;
  o.z = a.z + b.z + c.z + d.z + bb.z;
  o.w = a.w + b.w + c.w + d.w + bb.w;
  ((float4*)out)[i] = o;
}

extern "C" void kernel_launch(void* const* d_in, const int* in_sizes, int n_in,
                              void* d_out, int out_size, void* d_ws, size_t ws_size,
                              hipStream_t stream) {
  const float* in1 = (const float*)d_in[0];
  const float* in2 = (const float*)d_in[1];
  const float* in3 = (const float*)d_in[2];
  const float* Wq = (const float*)d_in[3];
  const float* bq = (const float*)d_in[4];
  const float* Wk = (const float*)d_in[5];
  const float* bk = (const float*)d_in[6];
  const float* Wv = (const float*)d_in[7];
  const float* bv = (const float*)d_in[8];
  const float* Wo = (const float*)d_in[9];
  const float* bo = (const float*)d_in[10];

  const long long MB = 1024 * 1024;
  typedef unsigned short us;
  unsigned char* w = (unsigned char*)d_ws;
  us* in2b = (us*)(w);                 // 8 MB  (X2 bf16; live through scores)
  us* Tbuf = (us*)(w + 8 * MB);        // 64 MB (T, then concat per-chunk)
  us* Vt = (us*)(w + 72 * MB);         // 64 MB (then out-proj partials)
  us* wvt = (us*)(w + 136 * MB);       // 4 MB  (dead after V-proj; partials overflow)
  us* wot = (us*)(w + 140 * MB);       // 4 MB
  us* scb = (us*)(w + 144 * MB);       // 64 MB (scores/P bf16, in-place)
  us* in1b = (us*)(w + 208 * MB);      // 8 MB
  us* in3b = (us*)(w + 216 * MB);      // 8 MB
  us* wqb = (us*)(w + 224 * MB);       // 4 MB
  us* wkb = (us*)(w + 228 * MB);       // 4 MB
  us* Gt = (us*)(w + 232 * MB);        // 4 MB
  float* rt = (float*)(w + 236 * MB);  // 256 KB
  float* ct = (float*)(w + 236 * MB + (256 << 10));
  float* ubuf = (float*)(w + 237 * MB);  // 16 KB
  float* vbuf = (float*)(w + 237 * MB + (16 << 10));
  float* cbuf = (float*)(w + 237 * MB + (32 << 10));
  float* partials = (float*)(w + 72 * MB);  // 67.1 MB over Vt+wvt
  if ((long long)ws_size < 238 * MB) return;

  const float iscale = 0.04419417382415922f;  // 1/sqrt(512)
  const long long SD = 1024 * 512;            // 524288

  // conversions / transposes
  k_conv_bf16<<<4096, 256, 0, stream>>>(in1, in1b, 1048576);
  k_conv_bf16<<<4096, 256, 0, stream>>>(in2, in2b, 1048576);
  k_conv_bf16<<<4096, 256, 0, stream>>>(in3, in3b, 1048576);
  k_conv_bf16<<<2048, 256, 0, stream>>>(Wq, wqb, 524288);
  k_conv_bf16<<<2048, 256, 0, stream>>>(Wk, wkb, 524288);
  k_transpose_bf16<<<dim3(16, 16, 8), dim3(32, 8), 0, stream>>>(Wv, wvt, 512, 512);
  k_transpose_bf16<<<dim3(16, 128, 1), dim3(32, 8), 0, stream>>>(Wo, wot, 4096, 512);

  // bias cross-terms: u = Wq bk, v = Wk bq, c = bq.bk, rt/ct row/col adds
  k_uv<<<dim3(1024, 2), 256, 0, stream>>>(Wq, bk, Wk, bq, ubuf, vbuf);
  k_bdot<<<1, 512, 0, stream>>>(bq, bk, cbuf);
  k_rtct<<<dim3(8192, 2), 256, 0, stream>>>(in1, in2, ubuf, vbuf, cbuf, rt, ct);

  // Gt[h] = Wk[h] Wq[h]^T  (so that T = X1 G with Bt=Gt)
  k_gemm_bt<1><<<dim3(4, 4, 8), 256, 0, stream>>>(
      wkb, wqb, Gt, nullptr, nullptr, nullptr, 512, 512, 512, 512,
      0, 7, 262144LL, 0, 7, 262144LL, 0, 262144LL, 0, 0, 0, 0, 0, 1.f);

  // T[z=b*8+h] = X1[b] G[h]   [64][1024][512] bf16
  k_gemm_bt<1><<<dim3(4, 8, 64), 256, 0, stream>>>(
      in1b, Gt, Tbuf, nullptr, nullptr, nullptr, 512, 512, 512, 512,
      3, 7, SD, 0, 7, 262144LL, 0, SD, 0, 0, 0, 0, 0, 1.f);

  // V-proj, transposed out: Vt[z][e][s]  [64][512][1024] bf16, +bv
  k_gemm_bt<2><<<dim3(4, 8, 64), 256, 0, stream>>>(
      in3b, wvt, Vt, bv, nullptr, nullptr, 512, 512, 512, 1024,
      3, 7, SD, 0, 7, 262144LL, 0, SD, 0, 0, 7, 512, 0, 1.f);

  // attention in 2 chunks of 4 batches (32 heads each)
  for (int c = 0; c < 2; ++c) {
    // scores[zz][i][j] = (T X2^T + rt + ct) * iscale  -> bf16
    k_gemm_bt<1><<<dim3(8, 8, 32), 256, 0, stream>>>(
        Tbuf + (long long)c * 32 * SD, in2b + (long long)c * 4 * SD, scb, nullptr,
        rt + c * 32768, ct + c * 32768, 512, 512, 512, 1024,
        0, 31, SD, 3, 3, SD, 0, 1048576LL, 0, 0, 0, 0, 1024, iscale);
    k_softmax_bf16<<<8192, 256, 0, stream>>>(scb);
    // heads -> concat[(c*4+b')*1024 + i][h*512 + e]  (concat aliases T chunk c, dead)
    k_gemm_bt<1><<<dim3(4, 8, 32), 256, 0, stream>>>(
        scb, Vt + (long long)c * 32 * SD, Tbuf + (long long)c * 16777216LL, nullptr,
        nullptr, nullptr, 1024, 1024, 1024, 4096,
        0, 31, 1048576LL, 0, 31, SD, 3, 4194304LL, 7, 512, 0, 0, 0, 1.f);
  }

  // out-proj split-K=4: partials[z] = concat[:, z*1024:(z+1)*1024] @ wot[:, z*1024:...]^T
  k_gemm_bt<0><<<dim3(4, 64, 4), 256, 0, stream>>>(
      Tbuf, wot, partials, nullptr, nullptr, nullptr, 1024, 4096, 4096, 512,
      0, 3, 1024LL, 0, 3, 1024LL, 0, 4194304LL, 0, 0, 0, 0, 0, 1.f);
  k_reduce4<<<4096, 256, 0, stream>>>(partials, bo, (float*)d_out);
}

// Round 3
// 671.086 us; speedup vs baseline: 1.0888x; 1.0559x over previous
//
#include <hip/hip_runtime.h>
#include <hip/hip_bf16.h>

#define DEV static __device__ __forceinline__

typedef float f32x4 __attribute__((ext_vector_type(4)));
typedef __bf16 b16x8 __attribute__((ext_vector_type(8)));

DEV unsigned short f2bf(float f) {
  union { __hip_bfloat16 h; unsigned short u; } cv;
  cv.h = __float2bfloat16(f);
  return cv.u;
}

DEV void gload_lds16(const unsigned short* g, unsigned short* l) {
  __builtin_amdgcn_global_load_lds(
      (__attribute__((address_space(1))) void*)g,
      (__attribute__((address_space(3))) void*)l, 16, 0, 0);
}

// ---------------- f32 -> bf16 elementwise ----------------
__global__ __launch_bounds__(256) void k_conv_bf16(const float* __restrict__ src,
                                                   unsigned short* __restrict__ dst,
                                                   long long n4) {
  long long i = (long long)blockIdx.x * 256 + threadIdx.x;
  if (i >= n4) return;
  const float4 v = ((const float4*)src)[i];
  ushort4 o;
  o.x = f2bf(v.x); o.y = f2bf(v.y); o.z = f2bf(v.z); o.w = f2bf(v.w);
  ((ushort4*)dst)[i] = o;
}

// ---------------- f32 [z][R][C] -> bf16 [z][C][R] ----------------
__global__ __launch_bounds__(256) void k_transpose_bf16(const float* __restrict__ src,
                                                        unsigned short* __restrict__ dst,
                                                        int R, int C) {
  __shared__ float t[32][33];
  const long long zo = (long long)blockIdx.z * R * C;
  const int c0 = blockIdx.x * 32, r0 = blockIdx.y * 32;
  const int tx = threadIdx.x, ty = threadIdx.y;
#pragma unroll
  for (int i = 0; i < 4; ++i)
    t[ty + i * 8][tx] = src[zo + (long long)(r0 + ty + i * 8) * C + c0 + tx];
  __syncthreads();
#pragma unroll
  for (int i = 0; i < 4; ++i)
    dst[zo + (long long)(c0 + ty + i * 8) * R + r0 + tx] = f2bf(t[tx][ty + i * 8]);
}

// ---------------- u[h,d]=sum_e Wq[h,d,e]*bk[h,e] (sel0) / v from Wk,bq (sel1) ----------------
__global__ __launch_bounds__(256) void k_uv(const float* __restrict__ Wq, const float* __restrict__ bk,
                                            const float* __restrict__ Wk, const float* __restrict__ bq,
                                            float* __restrict__ u, float* __restrict__ v) {
  const int sel = blockIdx.y;
  const float* W = sel ? Wk : Wq;
  const float* bb = sel ? bq : bk;
  float* dst = sel ? v : u;
  const int wave = threadIdx.x >> 6, lane = threadIdx.x & 63;
  const int idx = blockIdx.x * 4 + wave;
  const int h = idx >> 9, d = idx & 511;
  const float* wr = W + ((long long)h * 512 + d) * 512 + lane * 8;
  const float* br = bb + h * 512 + lane * 8;
  float s = 0.f;
#pragma unroll
  for (int k = 0; k < 8; ++k) s += wr[k] * br[k];
#pragma unroll
  for (int off = 32; off; off >>= 1) s += __shfl_xor(s, off);
  if (lane == 0) dst[h * 512 + d] = s;
}

// ---------------- c[h] = bq[h].bk[h] ----------------
__global__ __launch_bounds__(512) void k_bdot(const float* __restrict__ bq,
                                              const float* __restrict__ bk,
                                              float* __restrict__ c) {
  const int wave = threadIdx.x >> 6, lane = threadIdx.x & 63;
  const float* a = bq + wave * 512 + lane * 8;
  const float* b = bk + wave * 512 + lane * 8;
  float s = 0.f;
#pragma unroll
  for (int k = 0; k < 8; ++k) s += a[k] * b[k];
#pragma unroll
  for (int off = 32; off; off >>= 1) s += __shfl_xor(s, off);
  if (lane == 0) c[wave] = s;
}

// ---------------- rt[b*8+h][i] = in1[b,i,:].u[h,:] + c[h]; ct from in2,v ----------------
__global__ __launch_bounds__(256) void k_rtct(const float* __restrict__ in1, const float* __restrict__ in2,
                                              const float* __restrict__ u, const float* __restrict__ v,
                                              const float* __restrict__ cbuf,
                                              float* __restrict__ rt, float* __restrict__ ct) {
  const int sel = blockIdx.y;
  const float* src = sel ? in2 : in1;
  const float* vec = sel ? v : u;
  float* dst = sel ? ct : rt;
  const int row = blockIdx.x;
  __shared__ float x[512];
  const float* p = src + (long long)row * 512;
  x[threadIdx.x] = p[threadIdx.x];
  x[threadIdx.x + 256] = p[threadIdx.x + 256];
  __syncthreads();
  const int wave = threadIdx.x >> 6, lane = threadIdx.x & 63;
  const int b = row >> 10, i = row & 1023;
#pragma unroll
  for (int t = 0; t < 2; ++t) {
    const int h = wave * 2 + t;
    const float* wv = vec + h * 512;
    float s = 0.f;
#pragma unroll
    for (int k = 0; k < 8; ++k) s += x[lane + k * 64] * wv[lane + k * 64];
#pragma unroll
    for (int off = 32; off; off >>= 1) s += __shfl_xor(s, off);
    if (lane == 0)
      dst[((long long)(b * 8 + h)) * 1024 + i] = s + (sel ? 0.f : cbuf[h]);
  }
}

// ---------------- in-place row softmax over 1024 bf16, one wave per row ----------------
__global__ __launch_bounds__(256) void k_softmax_bf16(unsigned short* __restrict__ P) {
  const int wave = threadIdx.x >> 6, lane = threadIdx.x & 63;
  unsigned short* p = P + ((long long)blockIdx.x * 4 + wave) * 1024 + lane * 16;
  const b16x8 v0 = *(const b16x8*)p;
  const b16x8 v1 = *(const b16x8*)(p + 8);
  float f[16];
#pragma unroll
  for (int j = 0; j < 8; ++j) { f[j] = (float)v0[j]; f[8 + j] = (float)v1[j]; }
  float mx = f[0];
#pragma unroll
  for (int j = 1; j < 16; ++j) mx = fmaxf(mx, f[j]);
#pragma unroll
  for (int off = 32; off; off >>= 1) mx = fmaxf(mx, __shfl_xor(mx, off));
  float sum = 0.f;
#pragma unroll
  for (int j = 0; j < 16; ++j) { f[j] = __expf(f[j] - mx); sum += f[j]; }
#pragma unroll
  for (int off = 32; off; off >>= 1) sum += __shfl_xor(sum, off);
  const float inv = 1.f / sum;
  b16x8 o0, o1;
#pragma unroll
  for (int j = 0; j < 8; ++j) { o0[j] = (__bf16)(f[j] * inv); o1[j] = (__bf16)(f[8 + j] * inv); }
  *(b16x8*)p = o0;
  *(b16x8*)(p + 8) = o1;
}

// ---------------- old 128x128 GEMM (kept for the small Gt GEMM) ----------------
template <int OM>
__global__ __launch_bounds__(256) void k_gemm_bt(
    const unsigned short* __restrict__ A, const unsigned short* __restrict__ Bt,
    void* __restrict__ Cv, const float* __restrict__ bias,
    const float* __restrict__ rAdd, const float* __restrict__ cAdd,
    int K, int lda, int ldb, int ldc,
    int azs, int azm, long long azr,
    int bzs, int bzm, long long bzr,
    int czs, long long czr, int czm, int czc,
    int biasm, int bstr, int rstr, float scale) {
  __shared__ unsigned short lA[128 * 64];
  __shared__ unsigned short lB[128 * 64];
  const int tid = threadIdx.x, wave = tid >> 6, lane = tid & 63;
  const int z = blockIdx.z;
  const int m0 = blockIdx.y * 128, n0 = blockIdx.x * 128;
  const unsigned short* Az = A + (long long)((z >> azs) & azm) * azr + (long long)m0 * lda;
  const unsigned short* Bz = Bt + (long long)((z >> bzs) & bzm) * bzr + (long long)n0 * ldb;

  const int srow = wave * 32 + (lane >> 3);
  const int scol = (lane & 7) * 8;
  const unsigned short* ga = Az + (long long)srow * lda + scol;
  const unsigned short* gb = Bz + (long long)srow * ldb + scol;
  unsigned short* laBase = &lA[(wave * 32) * 64];
  unsigned short* lbBase = &lB[(wave * 32) * 64];

  f32x4 acc[4][4] = {};
  const int wr = (wave >> 1) * 64, wc = (wave & 1) * 64;
  const int fr = lane & 15, kq = (lane >> 4) * 8;

  for (int k0 = 0; k0 < K; k0 += 64) {
#pragma unroll
    for (int i = 0; i < 4; ++i) {
      gload_lds16(ga + (long long)(i * 8) * lda + k0, laBase + (i * 8) * 64);
      gload_lds16(gb + (long long)(i * 8) * ldb + k0, lbBase + (i * 8) * 64);
    }
    __syncthreads();
#pragma unroll
    for (int kk = 0; kk < 64; kk += 32) {
      b16x8 af[4], bf[4];
#pragma unroll
      for (int i = 0; i < 4; ++i)
        af[i] = *(const b16x8*)&lA[(wr + i * 16 + fr) * 64 + kk + kq];
#pragma unroll
      for (int j = 0; j < 4; ++j)
        bf[j] = *(const b16x8*)&lB[(wc + j * 16 + fr) * 64 + kk + kq];
#pragma unroll
      for (int i = 0; i < 4; ++i)
#pragma unroll
        for (int j = 0; j < 4; ++j)
          acc[i][j] = __builtin_amdgcn_mfma_f32_16x16x32_bf16(af[i], bf[j], acc[i][j], 0, 0, 0);
    }
    __syncthreads();
  }

  const long long coff = (long long)(z >> czs) * czr + (long long)(z & czm) * czc;
  const long long zr = (long long)z * rstr;
  const int rr = (lane >> 4) * 4;
#pragma unroll
  for (int j = 0; j < 4; ++j) {
    const int col = n0 + wc + j * 16 + fr;
    const float bval = bias ? bias[(long long)(z & biasm) * bstr + col] : 0.f;
    const float ca = cAdd ? cAdd[zr + col] : 0.f;
#pragma unroll
    for (int i = 0; i < 4; ++i) {
#pragma unroll
      for (int r = 0; r < 4; ++r) {
        const int row = m0 + wr + i * 16 + rr + r;
        const float ra = rAdd ? rAdd[zr + row] : 0.f;
        const float val = (acc[i][j][r] + ra + ca) * scale + bval;
        if constexpr (OM == 1) {
          ((unsigned short*)Cv)[coff + (long long)row * ldc + col] = f2bf(val);
        } else if constexpr (OM == 2) {
          ((unsigned short*)Cv)[coff + (long long)col * ldc + row] = f2bf(val);
        } else {
          ((float*)Cv)[coff + (long long)row * ldc + col] = val;
        }
      }
    }
  }
}

// ================= 256x256 8-phase counted-vmcnt GEMM =================
// C[M,N] = A[M,K] * Bt[N,K]^T, bf16 in, tile 256x256, BK=64, 512 threads
// (8 waves, 2M x 4N), LDS 128 KiB double-buffered, T2 col-XOR swizzle,
// per-phase setprio MFMA clusters, vmcnt(2) counted wait (drain only at end).
// Swizzle: LDS[r][x] holds global element (r, x ^ g(r)),
//          g(r) = ((r>>3)&1)<<4 | ((r>>2)&1)<<3  (8-col-group permute, 16B safe)
#define STAGE_A8(nb, koff, i)                                                        \
  gload_lds16(gaL + (long long)((i) * 8) * lda + (koff) + (colE ^ (((i) & 1) << 4)), \
              &lA[nb][(wid * 32 + (i) * 8) * 64])
#define STAGE_B8(nb, koff, i)                                                        \
  gload_lds16(gbL + (long long)((i) * 8) * ldb + (koff) + (colE ^ (((i) & 1) << 4)), \
              &lB[nb][(wid * 32 + (i) * 8) * 64])

template <int OM>
__global__ __launch_bounds__(512, 2) void k_gemm8p(
    const unsigned short* __restrict__ A, const unsigned short* __restrict__ Bt,
    void* __restrict__ Cv, const float* __restrict__ bias,
    const float* __restrict__ rAdd, const float* __restrict__ cAdd,
    int K, int lda, int ldb, int ldc,
    int azs, int azm, long long azr,
    int bzs, int bzm, long long bzr,
    int czs, long long czr, int czm, int czc,
    int biasm, int bstr, int rstr, float scale, int kzm, int kzr) {
  __shared__ unsigned short lA[2][256 * 64];
  __shared__ unsigned short lB[2][256 * 64];
  const int tid = threadIdx.x, wid = tid >> 6, lane = tid & 63;
  const int wm = wid >> 2, wn = wid & 3;
  const int z = blockIdx.z;
  const int m0 = blockIdx.y * 256, n0 = blockIdx.x * 256;
  const int kstart = (z & kzm) * kzr;
  const unsigned short* Az = A + (long long)((z >> azs) & azm) * azr + (long long)m0 * lda + kstart;
  const unsigned short* Bz = Bt + (long long)((z >> bzs) & bzm) * bzr + (long long)n0 * ldb + kstart;

  // staging: wave wid covers rows [wid*32, +32) of A and of B (4 insts each)
  const int colE = ((lane & 7) * 8) ^ (((lane >> 5) & 1) << 3);  // source col, even i
  const unsigned short* gaL = Az + (long long)(wid * 32 + (lane >> 3)) * lda;
  const unsigned short* gbL = Bz + (long long)(wid * 32 + (lane >> 3)) * ldb;

  // fragment read addressing
  const int fr = lane & 15, kq = (lane >> 4) * 8;
  const int fsw = (((fr >> 3) & 1) << 4) | (((fr >> 2) & 1) << 3);
  const int rc0 = kq ^ fsw;        // kstep 0 col
  const int rc1 = 32 + (kq ^ fsw); // kstep 1 col
  const int aBase = (wm * 128 + fr) * 64;
  const int bBase = (wn * 64 + fr) * 64;

  f32x4 acc[8][4] = {};
  b16x8 afr[4][2], bfr[4][2];
  const int NT = K >> 6;

  // prologue: stage tile 0 into buf 0
#pragma unroll
  for (int i = 0; i < 4; ++i) { STAGE_A8(0, 0, i); STAGE_B8(0, 0, i); }

  for (int kt = 0; kt < NT; ++kt) {
    const int cur = kt & 1, nb = cur ^ 1;
    const int ko = (kt + 1) << 6;
    const bool pre = (kt + 1 < NT);
    // ---- phase 0: wait tile kt, compute quadrant (Mlo x Nlo) ----
    if (pre) {
      STAGE_A8(nb, ko, 0); STAGE_A8(nb, ko, 1);
      asm volatile("s_waitcnt vmcnt(2)" ::: "memory");
    } else {
      asm volatile("s_waitcnt vmcnt(0)" ::: "memory");
    }
    __builtin_amdgcn_s_barrier();
    __builtin_amdgcn_sched_barrier(0);
#pragma unroll
    for (int i = 0; i < 4; ++i) {
      afr[i][0] = *(const b16x8*)&lA[cur][aBase + i * 1024 + rc0];
      afr[i][1] = *(const b16x8*)&lA[cur][aBase + i * 1024 + rc1];
    }
#pragma unroll
    for (int j = 0; j < 2; ++j) {
      bfr[j][0] = *(const b16x8*)&lB[cur][bBase + j * 1024 + rc0];
      bfr[j][1] = *(const b16x8*)&lB[cur][bBase + j * 1024 + rc1];
    }
    __builtin_amdgcn_s_setprio(1);
#pragma unroll
    for (int t = 0; t < 2; ++t)
#pragma unroll
      for (int i = 0; i < 4; ++i)
#pragma unroll
        for (int j = 0; j < 2; ++j)
          acc[i][j] = __builtin_amdgcn_mfma_f32_16x16x32_bf16(afr[i][t], bfr[j][t], acc[i][j], 0, 0, 0);
    __builtin_amdgcn_s_setprio(0);
    __builtin_amdgcn_sched_barrier(0);
    // ---- phase 1: (Mlo x Nhi) ----
    if (pre) { STAGE_A8(nb, ko, 2); STAGE_A8(nb, ko, 3); }
    __builtin_amdgcn_s_barrier();
#pragma unroll
    for (int j = 2; j < 4; ++j) {
      bfr[j][0] = *(const b16x8*)&lB[cur][bBase + j * 1024 + rc0];
      bfr[j][1] = *(const b16x8*)&lB[cur][bBase + j * 1024 + rc1];
    }
    __builtin_amdgcn_s_setprio(1);
#pragma unroll
    for (int t = 0; t < 2; ++t)
#pragma unroll
      for (int i = 0; i < 4; ++i)
#pragma unroll
      for (int j = 2; j < 4; ++j)
          acc[i][j] = __builtin_amdgcn_mfma_f32_16x16x32_bf16(afr[i][t], bfr[j][t], acc[i][j], 0, 0, 0);
    __builtin_amdgcn_s_setprio(0);
    __builtin_amdgcn_sched_barrier(0);
    // ---- phase 2: (Mhi x Nlo) ----
    if (pre) { STAGE_B8(nb, ko, 0); STAGE_B8(nb, ko, 1); }
    __builtin_amdgcn_s_barrier();
#pragma unroll
    for (int i = 0; i < 4; ++i) {
      afr[i][0] = *(const b16x8*)&lA[cur][aBase + (i + 4) * 1024 + rc0];
      afr[i][1] = *(const b16x8*)&lA[cur][aBase + (i + 4) * 1024 + rc1];
    }
    __builtin_amdgcn_s_setprio(1);
#pragma unroll
    for (int t = 0; t < 2; ++t)
#pragma unroll
      for (int i = 0; i < 4; ++i)
#pragma unroll
        for (int j = 0; j < 2; ++j)
          acc[i + 4][j] = __builtin_amdgcn_mfma_f32_16x16x32_bf16(afr[i][t], bfr[j][t], acc[i + 4][j], 0, 0, 0);
    __builtin_amdgcn_s_setprio(0);
    __builtin_amdgcn_sched_barrier(0);
    // ---- phase 3: (Mhi x Nhi) ----
    if (pre) { STAGE_B8(nb, ko, 2); STAGE_B8(nb, ko, 3); }
    __builtin_amdgcn_s_barrier();
    __builtin_amdgcn_s_setprio(1);
#pragma unroll
    for (int t = 0; t < 2; ++t)
#pragma unroll
      for (int i = 0; i < 4; ++i)
#pragma unroll
        for (int j = 2; j < 4; ++j)
          acc[i + 4][j] = __builtin_amdgcn_mfma_f32_16x16x32_bf16(afr[i][t], bfr[j][t], acc[i + 4][j], 0, 0, 0);
    __builtin_amdgcn_s_setprio(0);
    __builtin_amdgcn_s_barrier();  // end of tile: buf[cur] free for next-iter staging
  }

  const long long coff = (long long)(z >> czs) * czr + (long long)(z & czm) * czc;
  const long long zr = (long long)z * rstr;
  const int rr = (lane >> 4) * 4;
#pragma unroll
  for (int j = 0; j < 4; ++j) {
    const int col = n0 + wn * 64 + j * 16 + (lane & 15);
    const float bval = bias ? bias[(long long)(z & biasm) * bstr + col] : 0.f;
    const float ca = cAdd ? cAdd[zr + col] : 0.f;
#pragma unroll
    for (int i = 0; i < 8; ++i) {
#pragma unroll
      for (int r = 0; r < 4; ++r) {
        const int row = m0 + wm * 128 + i * 16 + rr + r;
        const float ra = rAdd ? rAdd[zr + row] : 0.f;
        const float val = (acc[i][j][r] + ra + ca) * scale + bval;
        if constexpr (OM == 1) {
          ((unsigned short*)Cv)[coff + (long long)row * ldc + col] = f2bf(val);
        } else if constexpr (OM == 2) {
          ((unsigned short*)Cv)[coff + (long long)col * ldc + row] = f2bf(val);
        } else {
          ((float*)Cv)[coff + (long long)row * ldc + col] = val;
        }
      }
    }
  }
}

// ---------------- out = sum of 4 f32 partials + bias(per 512 cols) ----------------
__global__ __launch_bounds__(256) void k_reduce4(const float* __restrict__ p,
                                                 const float* __restrict__ bo,
                                                 float* __restrict__ out) {
  const long long i = (long long)blockIdx.x * 256 + threadIdx.x;
  const float4* p4 = (const float4*)p;
  float4 a = p4[i], b = p4[i + 1048576], c = p4[i + 2097152], d = p4[i + 3145728];
  const float4 bb = ((const float4*)bo)[i & 127];
  float4 o;
  o.x = a.x + b.x + c.x + d.x + bb.x;
  o.y = a.y + b.y + c.y + d.y + bb.y;
  o.z = a.z + b.z + c.z + d.z + bb.z;
  o.w = a.w + b.w + c.w + d.w + bb.w;
  ((float4*)out)[i] = o;
}

extern "C" void kernel_launch(void* const* d_in, const int* in_sizes, int n_in,
                              void* d_out, int out_size, void* d_ws, size_t ws_size,
                              hipStream_t stream) {
  const float* in1 = (const float*)d_in[0];
  const float* in2 = (const float*)d_in[1];
  const float* in3 = (const float*)d_in[2];
  const float* Wq = (const float*)d_in[3];
  const float* bq = (const float*)d_in[4];
  const float* Wk = (const float*)d_in[5];
  const float* bk = (const float*)d_in[6];
  const float* Wv = (const float*)d_in[7];
  const float* bv = (const float*)d_in[8];
  const float* Wo = (const float*)d_in[9];
  const float* bo = (const float*)d_in[10];

  const long long MB = 1024 * 1024;
  typedef unsigned short us;
  unsigned char* w = (unsigned char*)d_ws;
  us* in2b = (us*)(w);                 // 8 MB
  us* Tbuf = (us*)(w + 8 * MB);        // 64 MB (T, then concat per-chunk)
  us* Vt = (us*)(w + 72 * MB);         // 64 MB (then out-proj partials)
  us* wvt = (us*)(w + 136 * MB);       // 4 MB
  us* wot = (us*)(w + 140 * MB);       // 4 MB
  us* scb = (us*)(w + 144 * MB);       // 64 MB (scores/P bf16, in-place)
  us* in1b = (us*)(w + 208 * MB);      // 8 MB
  us* in3b = (us*)(w + 216 * MB);      // 8 MB
  us* wqb = (us*)(w + 224 * MB);       // 4 MB
  us* wkb = (us*)(w + 228 * MB);       // 4 MB
  us* Gt = (us*)(w + 232 * MB);        // 4 MB
  float* rt = (float*)(w + 236 * MB);  // 256 KB
  float* ct = (float*)(w + 236 * MB + (256 << 10));
  float* ubuf = (float*)(w + 237 * MB);
  float* vbuf = (float*)(w + 237 * MB + (16 << 10));
  float* cbuf = (float*)(w + 237 * MB + (32 << 10));
  float* partials = (float*)(w + 72 * MB);  // 64 MB over Vt (dead by then)
  if ((long long)ws_size < 238 * MB) return;

  const float iscale = 0.04419417382415922f;  // 1/sqrt(512)
  const long long SD = 1024 * 512;            // 524288

  // conversions / transposes
  k_conv_bf16<<<4096, 256, 0, stream>>>(in1, in1b, 1048576);
  k_conv_bf16<<<4096, 256, 0, stream>>>(in2, in2b, 1048576);
  k_conv_bf16<<<4096, 256, 0, stream>>>(in3, in3b, 1048576);
  k_conv_bf16<<<2048, 256, 0, stream>>>(Wq, wqb, 524288);
  k_conv_bf16<<<2048, 256, 0, stream>>>(Wk, wkb, 524288);
  k_transpose_bf16<<<dim3(16, 16, 8), dim3(32, 8), 0, stream>>>(Wv, wvt, 512, 512);
  k_transpose_bf16<<<dim3(16, 128, 1), dim3(32, 8), 0, stream>>>(Wo, wot, 4096, 512);

  // bias cross-terms
  k_uv<<<dim3(1024, 2), 256, 0, stream>>>(Wq, bk, Wk, bq, ubuf, vbuf);
  k_bdot<<<1, 512, 0, stream>>>(bq, bk, cbuf);
  k_rtct<<<dim3(8192, 2), 256, 0, stream>>>(in1, in2, ubuf, vbuf, cbuf, rt, ct);

  // Gt[h] = Wk[h] Wq[h]^T  (small; old kernel)
  k_gemm_bt<1><<<dim3(4, 4, 8), 256, 0, stream>>>(
      wkb, wqb, Gt, nullptr, nullptr, nullptr, 512, 512, 512, 512,
      0, 7, 262144LL, 0, 7, 262144LL, 0, 262144LL, 0, 0, 0, 0, 0, 1.f);

  // T[z=b*8+h] = X1[b] G[h]   [64][1024][512] bf16
  k_gemm8p<1><<<dim3(2, 4, 64), 512, 0, stream>>>(
      in1b, Gt, Tbuf, nullptr, nullptr, nullptr, 512, 512, 512, 512,
      3, 7, SD, 0, 7, 262144LL, 0, SD, 0, 0, 0, 0, 0, 1.f, 0, 0);

  // V-proj transposed: Vt[z][e][s]  [64][512][1024] bf16, +bv
  k_gemm8p<2><<<dim3(2, 4, 64), 512, 0, stream>>>(
      in3b, wvt, Vt, bv, nullptr, nullptr, 512, 512, 512, 1024,
      3, 7, SD, 0, 7, 262144LL, 0, SD, 0, 0, 7, 512, 0, 1.f, 0, 0);

  // attention in 2 chunks of 4 batches (32 heads each)
  for (int c = 0; c < 2; ++c) {
    // scores[zz][i][j] = (T X2^T + rt + ct) * iscale -> bf16
    k_gemm8p<1><<<dim3(4, 4, 32), 512, 0, stream>>>(
        Tbuf + (long long)c * 32 * SD, in2b + (long long)c * 4 * SD, scb, nullptr,
        rt + c * 32768, ct + c * 32768, 512, 512, 512, 1024,
        0, 31, SD, 3, 3, SD, 0, 1048576LL, 0, 0, 0, 0, 1024, iscale, 0, 0);
    k_softmax_bf16<<<8192, 256, 0, stream>>>(scb);
    // heads -> concat[(c*4+b')*1024 + i][h*512 + e]
    k_gemm8p<1><<<dim3(2, 4, 32), 512, 0, stream>>>(
        scb, Vt + (long long)c * 32 * SD, Tbuf + (long long)c * 16777216LL, nullptr,
        nullptr, nullptr, 1024, 1024, 1024, 4096,
        0, 31, 1048576LL, 0, 31, SD, 3, 4194304LL, 7, 512, 0, 0, 0, 1.f, 0, 0);
  }

  // out-proj split-K=4: partials[ks] = concat[:, ks*1024:+1024] @ wot[:, same]^T
  k_gemm8p<0><<<dim3(2, 32, 4), 512, 0, stream>>>(
      Tbuf, wot, partials, nullptr, nullptr, nullptr, 1024, 4096, 4096, 512,
      0, 0, 0, 0, 0, 0, 0, 4194304LL, 0, 0, 0, 0, 0, 1.f, 3, 1024);
  k_reduce4<<<4096, 256, 0, stream>>>(partials, bo, (float*)d_out);
}

// Round 4
// 607.338 us; speedup vs baseline: 1.2031x; 1.1050x over previous
//
#include <hip/hip_runtime.h>
#include <hip/hip_bf16.h>

#define DEV static __device__ __forceinline__

typedef float f32x4 __attribute__((ext_vector_type(4)));
typedef __bf16 b16x8 __attribute__((ext_vector_type(8)));

DEV unsigned short f2bf(float f) {
  union { __hip_bfloat16 h; unsigned short u; } cv;
  cv.h = __float2bfloat16(f);
  return cv.u;
}

DEV void gload_lds16(const unsigned short* g, unsigned short* l) {
  __builtin_amdgcn_global_load_lds(
      (__attribute__((address_space(1))) void*)g,
      (__attribute__((address_space(3))) void*)l, 16, 0, 0);
}

// ---------------- f32 -> bf16 elementwise ----------------
__global__ __launch_bounds__(256) void k_conv_bf16(const float* __restrict__ src,
                                                   unsigned short* __restrict__ dst,
                                                   long long n4) {
  long long i = (long long)blockIdx.x * 256 + threadIdx.x;
  if (i >= n4) return;
  const float4 v = ((const float4*)src)[i];
  ushort4 o;
  o.x = f2bf(v.x); o.y = f2bf(v.y); o.z = f2bf(v.z); o.w = f2bf(v.w);
  ((ushort4*)dst)[i] = o;
}

// ---------------- f32 [z][R][C] -> bf16 [z][C][R] ----------------
__global__ __launch_bounds__(256) void k_transpose_bf16(const float* __restrict__ src,
                                                        unsigned short* __restrict__ dst,
                                                        int R, int C) {
  __shared__ float t[32][33];
  const long long zo = (long long)blockIdx.z * R * C;
  const int c0 = blockIdx.x * 32, r0 = blockIdx.y * 32;
  const int tx = threadIdx.x, ty = threadIdx.y;
#pragma unroll
  for (int i = 0; i < 4; ++i)
    t[ty + i * 8][tx] = src[zo + (long long)(r0 + ty + i * 8) * C + c0 + tx];
  __syncthreads();
#pragma unroll
  for (int i = 0; i < 4; ++i)
    dst[zo + (long long)(c0 + ty + i * 8) * R + r0 + tx] = f2bf(t[tx][ty + i * 8]);
}

// ---------------- u[h,d]=sum_e Wq[h,d,e]*bk[h,e] (sel0) / v from Wk,bq (sel1) ----------------
__global__ __launch_bounds__(256) void k_uv(const float* __restrict__ Wq, const float* __restrict__ bk,
                                            const float* __restrict__ Wk, const float* __restrict__ bq,
                                            float* __restrict__ u, float* __restrict__ v) {
  const int sel = blockIdx.y;
  const float* W = sel ? Wk : Wq;
  const float* bb = sel ? bq : bk;
  float* dst = sel ? v : u;
  const int wave = threadIdx.x >> 6, lane = threadIdx.x & 63;
  const int idx = blockIdx.x * 4 + wave;
  const int h = idx >> 9, d = idx & 511;
  const float* wr = W + ((long long)h * 512 + d) * 512 + lane * 8;
  const float* br = bb + h * 512 + lane * 8;
  float s = 0.f;
#pragma unroll
  for (int k = 0; k < 8; ++k) s += wr[k] * br[k];
#pragma unroll
  for (int off = 32; off; off >>= 1) s += __shfl_xor(s, off);
  if (lane == 0) dst[h * 512 + d] = s;
}

// ---------------- c[h] = bq[h].bk[h] ----------------
__global__ __launch_bounds__(512) void k_bdot(const float* __restrict__ bq,
                                              const float* __restrict__ bk,
                                              float* __restrict__ c) {
  const int wave = threadIdx.x >> 6, lane = threadIdx.x & 63;
  const float* a = bq + wave * 512 + lane * 8;
  const float* b = bk + wave * 512 + lane * 8;
  float s = 0.f;
#pragma unroll
  for (int k = 0; k < 8; ++k) s += a[k] * b[k];
#pragma unroll
  for (int off = 32; off; off >>= 1) s += __shfl_xor(s, off);
  if (lane == 0) c[wave] = s;
}

// ---------------- rt[b*8+h][i] = in1[b,i,:].u[h,:] + c[h]; ct from in2,v ----------------
__global__ __launch_bounds__(256) void k_rtct(const float* __restrict__ in1, const float* __restrict__ in2,
                                              const float* __restrict__ u, const float* __restrict__ v,
                                              const float* __restrict__ cbuf,
                                              float* __restrict__ rt, float* __restrict__ ct) {
  const int sel = blockIdx.y;
  const float* src = sel ? in2 : in1;
  const float* vec = sel ? v : u;
  float* dst = sel ? ct : rt;
  const int row = blockIdx.x;
  __shared__ float x[512];
  const float* p = src + (long long)row * 512;
  x[threadIdx.x] = p[threadIdx.x];
  x[threadIdx.x + 256] = p[threadIdx.x + 256];
  __syncthreads();
  const int wave = threadIdx.x >> 6, lane = threadIdx.x & 63;
  const int b = row >> 10, i = row & 1023;
#pragma unroll
  for (int t = 0; t < 2; ++t) {
    const int h = wave * 2 + t;
    const float* wv = vec + h * 512;
    float s = 0.f;
#pragma unroll
    for (int k = 0; k < 8; ++k) s += x[lane + k * 64] * wv[lane + k * 64];
#pragma unroll
    for (int off = 32; off; off >>= 1) s += __shfl_xor(s, off);
    if (lane == 0)
      dst[((long long)(b * 8 + h)) * 1024 + i] = s + (sel ? 0.f : cbuf[h]);
  }
}

// ---------------- in-place row softmax over 1024 bf16, one wave per row ----------------
__global__ __launch_bounds__(256) void k_softmax_bf16(unsigned short* __restrict__ P) {
  const int wave = threadIdx.x >> 6, lane = threadIdx.x & 63;
  unsigned short* p = P + ((long long)blockIdx.x * 4 + wave) * 1024 + lane * 16;
  const b16x8 v0 = *(const b16x8*)p;
  const b16x8 v1 = *(const b16x8*)(p + 8);
  float f[16];
#pragma unroll
  for (int j = 0; j < 8; ++j) { f[j] = (float)v0[j]; f[8 + j] = (float)v1[j]; }
  float mx = f[0];
#pragma unroll
  for (int j = 1; j < 16; ++j) mx = fmaxf(mx, f[j]);
#pragma unroll
  for (int off = 32; off; off >>= 1) mx = fmaxf(mx, __shfl_xor(mx, off));
  float sum = 0.f;
#pragma unroll
  for (int j = 0; j < 16; ++j) { f[j] = __expf(f[j] - mx); sum += f[j]; }
#pragma unroll
  for (int off = 32; off; off >>= 1) sum += __shfl_xor(sum, off);
  const float inv = 1.f / sum;
  b16x8 o0, o1;
#pragma unroll
  for (int j = 0; j < 8; ++j) { o0[j] = (__bf16)(f[j] * inv); o1[j] = (__bf16)(f[8 + j] * inv); }
  *(b16x8*)p = o0;
  *(b16x8*)(p + 8) = o1;
}

// ---------------- old 128x128 GEMM (kept for the small Gt GEMM) ----------------
template <int OM>
__global__ __launch_bounds__(256) void k_gemm_bt(
    const unsigned short* __restrict__ A, const unsigned short* __restrict__ Bt,
    void* __restrict__ Cv, const float* __restrict__ bias,
    const float* __restrict__ rAdd, const float* __restrict__ cAdd,
    int K, int lda, int ldb, int ldc,
    int azs, int azm, long long azr,
    int bzs, int bzm, long long bzr,
    int czs, long long czr, int czm, int czc,
    int biasm, int bstr, int rstr, float scale) {
  __shared__ unsigned short lA[128 * 64];
  __shared__ unsigned short lB[128 * 64];
  const int tid = threadIdx.x, wave = tid >> 6, lane = tid & 63;
  const int z = blockIdx.z;
  const int m0 = blockIdx.y * 128, n0 = blockIdx.x * 128;
  const unsigned short* Az = A + (long long)((z >> azs) & azm) * azr + (long long)m0 * lda;
  const unsigned short* Bz = Bt + (long long)((z >> bzs) & bzm) * bzr + (long long)n0 * ldb;

  const int srow = wave * 32 + (lane >> 3);
  const int scol = (lane & 7) * 8;
  const unsigned short* ga = Az + (long long)srow * lda + scol;
  const unsigned short* gb = Bz + (long long)srow * ldb + scol;
  unsigned short* laBase = &lA[(wave * 32) * 64];
  unsigned short* lbBase = &lB[(wave * 32) * 64];

  f32x4 acc[4][4] = {};
  const int wr = (wave >> 1) * 64, wc = (wave & 1) * 64;
  const int fr = lane & 15, kq = (lane >> 4) * 8;

  for (int k0 = 0; k0 < K; k0 += 64) {
#pragma unroll
    for (int i = 0; i < 4; ++i) {
      gload_lds16(ga + (long long)(i * 8) * lda + k0, laBase + (i * 8) * 64);
      gload_lds16(gb + (long long)(i * 8) * ldb + k0, lbBase + (i * 8) * 64);
    }
    __syncthreads();
#pragma unroll
    for (int kk = 0; kk < 64; kk += 32) {
      b16x8 af[4], bf[4];
#pragma unroll
      for (int i = 0; i < 4; ++i)
        af[i] = *(const b16x8*)&lA[(wr + i * 16 + fr) * 64 + kk + kq];
#pragma unroll
      for (int j = 0; j < 4; ++j)
        bf[j] = *(const b16x8*)&lB[(wc + j * 16 + fr) * 64 + kk + kq];
#pragma unroll
      for (int i = 0; i < 4; ++i)
#pragma unroll
        for (int j = 0; j < 4; ++j)
          acc[i][j] = __builtin_amdgcn_mfma_f32_16x16x32_bf16(af[i], bf[j], acc[i][j], 0, 0, 0);
    }
    __syncthreads();
  }

  const long long coff = (long long)(z >> czs) * czr + (long long)(z & czm) * czc;
  const long long zr = (long long)z * rstr;
  const int rr = (lane >> 4) * 4;
#pragma unroll
  for (int j = 0; j < 4; ++j) {
    const int col = n0 + wc + j * 16 + fr;
    const float bval = bias ? bias[(long long)(z & biasm) * bstr + col] : 0.f;
    const float ca = cAdd ? cAdd[zr + col] : 0.f;
#pragma unroll
    for (int i = 0; i < 4; ++i) {
#pragma unroll
      for (int r = 0; r < 4; ++r) {
        const int row = m0 + wr + i * 16 + rr + r;
        const float ra = rAdd ? rAdd[zr + row] : 0.f;
        const float val = (acc[i][j][r] + ra + ca) * scale + bval;
        if constexpr (OM == 1) {
          ((unsigned short*)Cv)[coff + (long long)row * ldc + col] = f2bf(val);
        } else if constexpr (OM == 2) {
          ((unsigned short*)Cv)[coff + (long long)col * ldc + row] = f2bf(val);
        } else {
          ((float*)Cv)[coff + (long long)row * ldc + col] = val;
        }
      }
    }
  }
}

// ================= 256x256 8-phase counted-vmcnt GEMM =================
// C[M,N] = A[M,K] * Bt[N,K]^T, bf16 in, tile 256x256, BK=64, 512 threads
// (8 waves, 2M x 4N), LDS 128 KiB double-buffered, conflict-free XOR swizzle,
// per-phase setprio MFMA clusters, vmcnt(2) counted wait (drain only at end).
// Swizzle (elements): LDS[r][c] holds global (r, c ^ ((r&7)<<3)) — rotates the
// eight 16B quads of each 128B row by (r&7); 16-row same-col reads hit every
// bank exactly 8x (2-way aliasing only = free). Stage source col is the same
// involution applied per-lane (quad (l&7)^(l>>3)); 128B-row coalescing kept.
#define STAGE_A8(nb, koff, i)                                  \
  gload_lds16(gaL + (long long)((i) * 8) * lda + (koff) + scol, \
              &lA[nb][(wid * 32 + (i) * 8) * 64])
#define STAGE_B8(nb, koff, i)                                  \
  gload_lds16(gbL + (long long)((i) * 8) * ldb + (koff) + scol, \
              &lB[nb][(wid * 32 + (i) * 8) * 64])

template <int OM>
__global__ __launch_bounds__(512, 2) void k_gemm8p(
    const unsigned short* __restrict__ A, const unsigned short* __restrict__ Bt,
    void* __restrict__ Cv, const float* __restrict__ bias,
    const float* __restrict__ rAdd, const float* __restrict__ cAdd,
    int K, int lda, int ldb, int ldc,
    int azs, int azm, long long azr,
    int bzs, int bzm, long long bzr,
    int czs, long long czr, int czm, int czc,
    int biasm, int bstr, int rstr, float scale, int kzm, int kzr) {
  __shared__ unsigned short lA[2][256 * 64];
  __shared__ unsigned short lB[2][256 * 64];
  const int tid = threadIdx.x, wid = tid >> 6, lane = tid & 63;
  const int wm = wid >> 2, wn = wid & 3;
  const int z = blockIdx.z;
  const int m0 = blockIdx.y * 256, n0 = blockIdx.x * 256;
  const int kstart = (z & kzm) * kzr;
  const unsigned short* Az = A + (long long)((z >> azs) & azm) * azr + (long long)m0 * lda + kstart;
  const unsigned short* Bz = Bt + (long long)((z >> bzs) & bzm) * bzr + (long long)n0 * ldb + kstart;

  // staging: wave wid covers rows [wid*32, +32) of A and of B (4 insts each);
  // per-lane source col quad = (l&7) ^ (l>>3)  (the read-side involution)
  const int scol = (((lane & 7) ^ ((lane >> 3) & 7)) << 3);
  const unsigned short* gaL = Az + (long long)(wid * 32 + (lane >> 3)) * lda;
  const unsigned short* gbL = Bz + (long long)(wid * 32 + (lane >> 3)) * ldb;

  // fragment read addressing: row = ..+fr, col = (kq + t*32) ^ ((fr&7)<<3)
  const int fr = lane & 15, kq = (lane >> 4) * 8;
  const int fsw = (fr & 7) << 3;
  const int rc0 = kq ^ fsw;         // kstep 0 col
  const int rc1 = (32 + kq) ^ fsw;  // kstep 1 col
  const int aBase = (wm * 128 + fr) * 64;
  const int bBase = (wn * 64 + fr) * 64;

  f32x4 acc[8][4] = {};
  b16x8 afr[4][2], bfr[4][2];
  const int NT = K >> 6;

  // prologue: stage tile 0 into buf 0
#pragma unroll
  for (int i = 0; i < 4; ++i) { STAGE_A8(0, 0, i); STAGE_B8(0, 0, i); }

  for (int kt = 0; kt < NT; ++kt) {
    const int cur = kt & 1, nb = cur ^ 1;
    const int ko = (kt + 1) << 6;
    const bool pre = (kt + 1 < NT);
    // ---- phase 0: wait tile kt, compute quadrant (Mlo x Nlo) ----
    if (pre) {
      STAGE_A8(nb, ko, 0); STAGE_A8(nb, ko, 1);
      asm volatile("s_waitcnt vmcnt(2)" ::: "memory");
    } else {
      asm volatile("s_waitcnt vmcnt(0)" ::: "memory");
    }
    __builtin_amdgcn_s_barrier();
    __builtin_amdgcn_sched_barrier(0);
#pragma unroll
    for (int i = 0; i < 4; ++i) {
      afr[i][0] = *(const b16x8*)&lA[cur][aBase + i * 1024 + rc0];
      afr[i][1] = *(const b16x8*)&lA[cur][aBase + i * 1024 + rc1];
    }
#pragma unroll
    for (int j = 0; j < 2; ++j) {
      bfr[j][0] = *(const b16x8*)&lB[cur][bBase + j * 1024 + rc0];
      bfr[j][1] = *(const b16x8*)&lB[cur][bBase + j * 1024 + rc1];
    }
    __builtin_amdgcn_s_setprio(1);
#pragma unroll
    for (int t = 0; t < 2; ++t)
#pragma unroll
      for (int i = 0; i < 4; ++i)
#pragma unroll
        for (int j = 0; j < 2; ++j)
          acc[i][j] = __builtin_amdgcn_mfma_f32_16x16x32_bf16(afr[i][t], bfr[j][t], acc[i][j], 0, 0, 0);
    __builtin_amdgcn_s_setprio(0);
    __builtin_amdgcn_sched_barrier(0);
    // ---- phase 1: (Mlo x Nhi) ----
    if (pre) { STAGE_A8(nb, ko, 2); STAGE_A8(nb, ko, 3); }
    __builtin_amdgcn_s_barrier();
#pragma unroll
    for (int j = 2; j < 4; ++j) {
      bfr[j][0] = *(const b16x8*)&lB[cur][bBase + j * 1024 + rc0];
      bfr[j][1] = *(const b16x8*)&lB[cur][bBase + j * 1024 + rc1];
    }
    __builtin_amdgcn_s_setprio(1);
#pragma unroll
    for (int t = 0; t < 2; ++t)
#pragma unroll
      for (int i = 0; i < 4; ++i)
#pragma unroll
      for (int j = 2; j < 4; ++j)
          acc[i][j] = __builtin_amdgcn_mfma_f32_16x16x32_bf16(afr[i][t], bfr[j][t], acc[i][j], 0, 0, 0);
    __builtin_amdgcn_s_setprio(0);
    __builtin_amdgcn_sched_barrier(0);
    // ---- phase 2: (Mhi x Nlo) ----
    if (pre) { STAGE_B8(nb, ko, 0); STAGE_B8(nb, ko, 1); }
    __builtin_amdgcn_s_barrier();
#pragma unroll
    for (int i = 0; i < 4; ++i) {
      afr[i][0] = *(const b16x8*)&lA[cur][aBase + (i + 4) * 1024 + rc0];
      afr[i][1] = *(const b16x8*)&lA[cur][aBase + (i + 4) * 1024 + rc1];
    }
    __builtin_amdgcn_s_setprio(1);
#pragma unroll
    for (int t = 0; t < 2; ++t)
#pragma unroll
      for (int i = 0; i < 4; ++i)
#pragma unroll
        for (int j = 0; j < 2; ++j)
          acc[i + 4][j] = __builtin_amdgcn_mfma_f32_16x16x32_bf16(afr[i][t], bfr[j][t], acc[i + 4][j], 0, 0, 0);
    __builtin_amdgcn_s_setprio(0);
    __builtin_amdgcn_sched_barrier(0);
    // ---- phase 3: (Mhi x Nhi) ----
    if (pre) { STAGE_B8(nb, ko, 2); STAGE_B8(nb, ko, 3); }
    __builtin_amdgcn_s_barrier();
    __builtin_amdgcn_s_setprio(1);
#pragma unroll
    for (int t = 0; t < 2; ++t)
#pragma unroll
      for (int i = 0; i < 4; ++i)
#pragma unroll
        for (int j = 2; j < 4; ++j)
          acc[i + 4][j] = __builtin_amdgcn_mfma_f32_16x16x32_bf16(afr[i][t], bfr[j][t], acc[i + 4][j], 0, 0, 0);
    __builtin_amdgcn_s_setprio(0);
    __builtin_amdgcn_s_barrier();  // end of tile: buf[cur] free for next-iter staging
  }

  const long long coff = (long long)(z >> czs) * czr + (long long)(z & czm) * czc;
  const long long zr = (long long)z * rstr;
  const int rr = (lane >> 4) * 4;
#pragma unroll
  for (int j = 0; j < 4; ++j) {
    const int col = n0 + wn * 64 + j * 16 + (lane & 15);
    const float bval = bias ? bias[(long long)(z & biasm) * bstr + col] : 0.f;
    const float ca = cAdd ? cAdd[zr + col] : 0.f;
#pragma unroll
    for (int i = 0; i < 8; ++i) {
#pragma unroll
      for (int r = 0; r < 4; ++r) {
        const int row = m0 + wm * 128 + i * 16 + rr + r;
        const float ra = rAdd ? rAdd[zr + row] : 0.f;
        const float val = (acc[i][j][r] + ra + ca) * scale + bval;
        if constexpr (OM == 1) {
          ((unsigned short*)Cv)[coff + (long long)row * ldc + col] = f2bf(val);
        } else if constexpr (OM == 2) {
          ((unsigned short*)Cv)[coff + (long long)col * ldc + row] = f2bf(val);
        } else {
          ((float*)Cv)[coff + (long long)row * ldc + col] = val;
        }
      }
    }
  }
}

// ---------------- out = sum of 4 f32 partials + bias(per 512 cols) ----------------
__global__ __launch_bounds__(256) void k_reduce4(const float* __restrict__ p,
                                                 const float* __restrict__ bo,
                                                 float* __restrict__ out) {
  const long long i = (long long)blockIdx.x * 256 + threadIdx.x;
  const float4* p4 = (const float4*)p;
  float4 a = p4[i], b = p4[i + 1048576], c = p4[i + 2097152], d = p4[i + 3145728];
  const float4 bb = ((const float4*)bo)[i & 127];
  float4 o;
  o.x = a.x + b.x + c.x + d.x + bb.x;
  o.y = a.y + b.y + c.y + d.y + bb.y;
  o.z = a.z + b.z + c.z + d.z + bb.z;
  o.w = a.w + b.w + c.w + d.w + bb.w;
  ((float4*)out)[i] = o;
}

extern "C" void kernel_launch(void* const* d_in, const int* in_sizes, int n_in,
                              void* d_out, int out_size, void* d_ws, size_t ws_size,
                              hipStream_t stream) {
  const float* in1 = (const float*)d_in[0];
  const float* in2 = (const float*)d_in[1];
  const float* in3 = (const float*)d_in[2];
  const float* Wq = (const float*)d_in[3];
  const float* bq = (const float*)d_in[4];
  const float* Wk = (const float*)d_in[5];
  const float* bk = (const float*)d_in[6];
  const float* Wv = (const float*)d_in[7];
  const float* bv = (const float*)d_in[8];
  const float* Wo = (const float*)d_in[9];
  const float* bo = (const float*)d_in[10];

  const long long MB = 1024 * 1024;
  typedef unsigned short us;
  unsigned char* w = (unsigned char*)d_ws;
  us* in2b = (us*)(w);                 // 8 MB
  us* Tbuf = (us*)(w + 8 * MB);        // 64 MB (T, then concat per-chunk)
  us* Vt = (us*)(w + 72 * MB);         // 64 MB (then out-proj partials)
  us* wvt = (us*)(w + 136 * MB);       // 4 MB
  us* wot = (us*)(w + 140 * MB);       // 4 MB
  us* scb = (us*)(w + 144 * MB);       // 64 MB (scores/P bf16, in-place)
  us* in1b = (us*)(w + 208 * MB);      // 8 MB
  us* in3b = (us*)(w + 216 * MB);      // 8 MB
  us* wqb = (us*)(w + 224 * MB);       // 4 MB
  us* wkb = (us*)(w + 228 * MB);       // 4 MB
  us* Gt = (us*)(w + 232 * MB);        // 4 MB
  float* rt = (float*)(w + 236 * MB);  // 256 KB
  float* ct = (float*)(w + 236 * MB + (256 << 10));
  float* ubuf = (float*)(w + 237 * MB);
  float* vbuf = (float*)(w + 237 * MB + (16 << 10));
  float* cbuf = (float*)(w + 237 * MB + (32 << 10));
  float* partials = (float*)(w + 72 * MB);  // 64 MB over Vt (dead by then)
  if ((long long)ws_size < 238 * MB) return;

  const float iscale = 0.04419417382415922f;  // 1/sqrt(512)
  const long long SD = 1024 * 512;            // 524288

  // conversions / transposes
  k_conv_bf16<<<4096, 256, 0, stream>>>(in1, in1b, 1048576);
  k_conv_bf16<<<4096, 256, 0, stream>>>(in2, in2b, 1048576);
  k_conv_bf16<<<4096, 256, 0, stream>>>(in3, in3b, 1048576);
  k_conv_bf16<<<2048, 256, 0, stream>>>(Wq, wqb, 524288);
  k_conv_bf16<<<2048, 256, 0, stream>>>(Wk, wkb, 524288);
  k_transpose_bf16<<<dim3(16, 16, 8), dim3(32, 8), 0, stream>>>(Wv, wvt, 512, 512);
  k_transpose_bf16<<<dim3(16, 128, 1), dim3(32, 8), 0, stream>>>(Wo, wot, 4096, 512);

  // bias cross-terms
  k_uv<<<dim3(1024, 2), 256, 0, stream>>>(Wq, bk, Wk, bq, ubuf, vbuf);
  k_bdot<<<1, 512, 0, stream>>>(bq, bk, cbuf);
  k_rtct<<<dim3(8192, 2), 256, 0, stream>>>(in1, in2, ubuf, vbuf, cbuf, rt, ct);

  // Gt[h] = Wk[h] Wq[h]^T  (small; old kernel)
  k_gemm_bt<1><<<dim3(4, 4, 8), 256, 0, stream>>>(
      wkb, wqb, Gt, nullptr, nullptr, nullptr, 512, 512, 512, 512,
      0, 7, 262144LL, 0, 7, 262144LL, 0, 262144LL, 0, 0, 0, 0, 0, 1.f);

  // T[z=b*8+h] = X1[b] G[h]   [64][1024][512] bf16
  k_gemm8p<1><<<dim3(2, 4, 64), 512, 0, stream>>>(
      in1b, Gt, Tbuf, nullptr, nullptr, nullptr, 512, 512, 512, 512,
      3, 7, SD, 0, 7, 262144LL, 0, SD, 0, 0, 0, 0, 0, 1.f, 0, 0);

  // V-proj transposed: Vt[z][e][s]  [64][512][1024] bf16, +bv
  k_gemm8p<2><<<dim3(2, 4, 64), 512, 0, stream>>>(
      in3b, wvt, Vt, bv, nullptr, nullptr, 512, 512, 512, 1024,
      3, 7, SD, 0, 7, 262144LL, 0, SD, 0, 0, 7, 512, 0, 1.f, 0, 0);

  // attention in 2 chunks of 4 batches (32 heads each)
  for (int c = 0; c < 2; ++c) {
    // scores[zz][i][j] = (T X2^T + rt + ct) * iscale -> bf16
    k_gemm8p<1><<<dim3(4, 4, 32), 512, 0, stream>>>(
        Tbuf + (long long)c * 32 * SD, in2b + (long long)c * 4 * SD, scb, nullptr,
        rt + c * 32768, ct + c * 32768, 512, 512, 512, 1024,
        0, 31, SD, 3, 3, SD, 0, 1048576LL, 0, 0, 0, 0, 1024, iscale, 0, 0);
    k_softmax_bf16<<<8192, 256, 0, stream>>>(scb);
    // heads -> concat[(c*4+b')*1024 + i][h*512 + e]
    k_gemm8p<1><<<dim3(2, 4, 32), 512, 0, stream>>>(
        scb, Vt + (long long)c * 32 * SD, Tbuf + (long long)c * 16777216LL, nullptr,
        nullptr, nullptr, 1024, 1024, 1024, 4096,
        0, 31, 1048576LL, 0, 31, SD, 3, 4194304LL, 7, 512, 0, 0, 0, 1.f, 0, 0);
  }

  // out-proj split-K=4: partials[ks] = concat[:, ks*1024:+1024] @ wot[:, same]^T
  k_gemm8p<0><<<dim3(2, 32, 4), 512, 0, stream>>>(
      Tbuf, wot, partials, nullptr, nullptr, nullptr, 1024, 4096, 4096, 512,
      0, 0, 0, 0, 0, 0, 0, 4194304LL, 0, 0, 0, 0, 0, 1.f, 3, 1024);
  k_reduce4<<<4096, 256, 0, stream>>>(partials, bo, (float*)d_out);
}

// Round 5
// 590.924 us; speedup vs baseline: 1.2365x; 1.0278x over previous
//
#include <hip/hip_runtime.h>
#include <hip/hip_bf16.h>

#define DEV static __device__ __forceinline__

typedef float f32x4 __attribute__((ext_vector_type(4)));
typedef __bf16 b16x8 __attribute__((ext_vector_type(8)));

DEV unsigned short f2bf(float f) {
  union { __hip_bfloat16 h; unsigned short u; } cv;
  cv.h = __float2bfloat16(f);
  return cv.u;
}

DEV void gload_lds16(const unsigned short* g, unsigned short* l) {
  __builtin_amdgcn_global_load_lds(
      (__attribute__((address_space(1))) void*)g,
      (__attribute__((address_space(3))) void*)l, 16, 0, 0);
}

// ---------------- f32 -> bf16 elementwise ----------------
__global__ __launch_bounds__(256) void k_conv_bf16(const float* __restrict__ src,
                                                   unsigned short* __restrict__ dst,
                                                   long long n4) {
  long long i = (long long)blockIdx.x * 256 + threadIdx.x;
  if (i >= n4) return;
  const float4 v = ((const float4*)src)[i];
  ushort4 o;
  o.x = f2bf(v.x); o.y = f2bf(v.y); o.z = f2bf(v.z); o.w = f2bf(v.w);
  ((ushort4*)dst)[i] = o;
}

// ---------------- f32 [z][R][C] -> bf16 [z][C][R] ----------------
__global__ __launch_bounds__(256) void k_transpose_bf16(const float* __restrict__ src,
                                                        unsigned short* __restrict__ dst,
                                                        int R, int C) {
  __shared__ float t[32][33];
  const long long zo = (long long)blockIdx.z * R * C;
  const int c0 = blockIdx.x * 32, r0 = blockIdx.y * 32;
  const int tx = threadIdx.x, ty = threadIdx.y;
#pragma unroll
  for (int i = 0; i < 4; ++i)
    t[ty + i * 8][tx] = src[zo + (long long)(r0 + ty + i * 8) * C + c0 + tx];
  __syncthreads();
#pragma unroll
  for (int i = 0; i < 4; ++i)
    dst[zo + (long long)(c0 + ty + i * 8) * R + r0 + tx] = f2bf(t[tx][ty + i * 8]);
}

// ---------------- u[h,d]=sum_e Wq[h,d,e]*bk[h,e] (sel0) / v from Wk,bq (sel1) ----------------
__global__ __launch_bounds__(256) void k_uv(const float* __restrict__ Wq, const float* __restrict__ bk,
                                            const float* __restrict__ Wk, const float* __restrict__ bq,
                                            float* __restrict__ u, float* __restrict__ v) {
  const int sel = blockIdx.y;
  const float* W = sel ? Wk : Wq;
  const float* bb = sel ? bq : bk;
  float* dst = sel ? v : u;
  const int wave = threadIdx.x >> 6, lane = threadIdx.x & 63;
  const int idx = blockIdx.x * 4 + wave;
  const int h = idx >> 9, d = idx & 511;
  const float* wr = W + ((long long)h * 512 + d) * 512 + lane * 8;
  const float* br = bb + h * 512 + lane * 8;
  float s = 0.f;
#pragma unroll
  for (int k = 0; k < 8; ++k) s += wr[k] * br[k];
#pragma unroll
  for (int off = 32; off; off >>= 1) s += __shfl_xor(s, off);
  if (lane == 0) dst[h * 512 + d] = s;
}

// ---------------- c[h] = bq[h].bk[h] ----------------
__global__ __launch_bounds__(512) void k_bdot(const float* __restrict__ bq,
                                              const float* __restrict__ bk,
                                              float* __restrict__ c) {
  const int wave = threadIdx.x >> 6, lane = threadIdx.x & 63;
  const float* a = bq + wave * 512 + lane * 8;
  const float* b = bk + wave * 512 + lane * 8;
  float s = 0.f;
#pragma unroll
  for (int k = 0; k < 8; ++k) s += a[k] * b[k];
#pragma unroll
  for (int off = 32; off; off >>= 1) s += __shfl_xor(s, off);
  if (lane == 0) c[wave] = s;
}

// ---------------- rt[b*8+h][i] = in1[b,i,:].u[h,:] + c[h]; ct from in2,v ----------------
__global__ __launch_bounds__(256) void k_rtct(const float* __restrict__ in1, const float* __restrict__ in2,
                                              const float* __restrict__ u, const float* __restrict__ v,
                                              const float* __restrict__ cbuf,
                                              float* __restrict__ rt, float* __restrict__ ct) {
  const int sel = blockIdx.y;
  const float* src = sel ? in2 : in1;
  const float* vec = sel ? v : u;
  float* dst = sel ? ct : rt;
  const int row = blockIdx.x;
  __shared__ float x[512];
  const float* p = src + (long long)row * 512;
  x[threadIdx.x] = p[threadIdx.x];
  x[threadIdx.x + 256] = p[threadIdx.x + 256];
  __syncthreads();
  const int wave = threadIdx.x >> 6, lane = threadIdx.x & 63;
  const int b = row >> 10, i = row & 1023;
#pragma unroll
  for (int t = 0; t < 2; ++t) {
    const int h = wave * 2 + t;
    const float* wv = vec + h * 512;
    float s = 0.f;
#pragma unroll
    for (int k = 0; k < 8; ++k) s += x[lane + k * 64] * wv[lane + k * 64];
#pragma unroll
    for (int off = 32; off; off >>= 1) s += __shfl_xor(s, off);
    if (lane == 0)
      dst[((long long)(b * 8 + h)) * 1024 + i] = s + (sel ? 0.f : cbuf[h]);
  }
}

// ---------------- in-place row softmax over 1024 bf16, one wave per row ----------------
__global__ __launch_bounds__(256) void k_softmax_bf16(unsigned short* __restrict__ P) {
  const int wave = threadIdx.x >> 6, lane = threadIdx.x & 63;
  unsigned short* p = P + ((long long)blockIdx.x * 4 + wave) * 1024 + lane * 16;
  const b16x8 v0 = *(const b16x8*)p;
  const b16x8 v1 = *(const b16x8*)(p + 8);
  float f[16];
#pragma unroll
  for (int j = 0; j < 8; ++j) { f[j] = (float)v0[j]; f[8 + j] = (float)v1[j]; }
  float mx = f[0];
#pragma unroll
  for (int j = 1; j < 16; ++j) mx = fmaxf(mx, f[j]);
#pragma unroll
  for (int off = 32; off; off >>= 1) mx = fmaxf(mx, __shfl_xor(mx, off));
  float sum = 0.f;
#pragma unroll
  for (int j = 0; j < 16; ++j) { f[j] = __expf(f[j] - mx); sum += f[j]; }
#pragma unroll
  for (int off = 32; off; off >>= 1) sum += __shfl_xor(sum, off);
  const float inv = 1.f / sum;
  b16x8 o0, o1;
#pragma unroll
  for (int j = 0; j < 8; ++j) { o0[j] = (__bf16)(f[j] * inv); o1[j] = (__bf16)(f[8 + j] * inv); }
  *(b16x8*)p = o0;
  *(b16x8*)(p + 8) = o1;
}

// ---------------- old 128x128 GEMM (kept for the small Gt GEMM) ----------------
template <int OM>
__global__ __launch_bounds__(256) void k_gemm_bt(
    const unsigned short* __restrict__ A, const unsigned short* __restrict__ Bt,
    void* __restrict__ Cv, const float* __restrict__ bias,
    const float* __restrict__ rAdd, const float* __restrict__ cAdd,
    int K, int lda, int ldb, int ldc,
    int azs, int azm, long long azr,
    int bzs, int bzm, long long bzr,
    int czs, long long czr, int czm, int czc,
    int biasm, int bstr, int rstr, float scale) {
  __shared__ unsigned short lA[128 * 64];
  __shared__ unsigned short lB[128 * 64];
  const int tid = threadIdx.x, wave = tid >> 6, lane = tid & 63;
  const int z = blockIdx.z;
  const int m0 = blockIdx.y * 128, n0 = blockIdx.x * 128;
  const unsigned short* Az = A + (long long)((z >> azs) & azm) * azr + (long long)m0 * lda;
  const unsigned short* Bz = Bt + (long long)((z >> bzs) & bzm) * bzr + (long long)n0 * ldb;

  const int srow = wave * 32 + (lane >> 3);
  const int scol = (lane & 7) * 8;
  const unsigned short* ga = Az + (long long)srow * lda + scol;
  const unsigned short* gb = Bz + (long long)srow * ldb + scol;
  unsigned short* laBase = &lA[(wave * 32) * 64];
  unsigned short* lbBase = &lB[(wave * 32) * 64];

  f32x4 acc[4][4] = {};
  const int wr = (wave >> 1) * 64, wc = (wave & 1) * 64;
  const int fr = lane & 15, kq = (lane >> 4) * 8;

  for (int k0 = 0; k0 < K; k0 += 64) {
#pragma unroll
    for (int i = 0; i < 4; ++i) {
      gload_lds16(ga + (long long)(i * 8) * lda + k0, laBase + (i * 8) * 64);
      gload_lds16(gb + (long long)(i * 8) * ldb + k0, lbBase + (i * 8) * 64);
    }
    __syncthreads();
#pragma unroll
    for (int kk = 0; kk < 64; kk += 32) {
      b16x8 af[4], bf[4];
#pragma unroll
      for (int i = 0; i < 4; ++i)
        af[i] = *(const b16x8*)&lA[(wr + i * 16 + fr) * 64 + kk + kq];
#pragma unroll
      for (int j = 0; j < 4; ++j)
        bf[j] = *(const b16x8*)&lB[(wc + j * 16 + fr) * 64 + kk + kq];
#pragma unroll
      for (int i = 0; i < 4; ++i)
#pragma unroll
        for (int j = 0; j < 4; ++j)
          acc[i][j] = __builtin_amdgcn_mfma_f32_16x16x32_bf16(af[i], bf[j], acc[i][j], 0, 0, 0);
    }
    __syncthreads();
  }

  const long long coff = (long long)(z >> czs) * czr + (long long)(z & czm) * czc;
  const long long zr = (long long)z * rstr;
  const int rr = (lane >> 4) * 4;
#pragma unroll
  for (int j = 0; j < 4; ++j) {
    const int col = n0 + wc + j * 16 + fr;
    const float bval = bias ? bias[(long long)(z & biasm) * bstr + col] : 0.f;
    const float ca = cAdd ? cAdd[zr + col] : 0.f;
#pragma unroll
    for (int i = 0; i < 4; ++i) {
#pragma unroll
      for (int r = 0; r < 4; ++r) {
        const int row = m0 + wr + i * 16 + rr + r;
        const float ra = rAdd ? rAdd[zr + row] : 0.f;
        const float val = (acc[i][j][r] + ra + ca) * scale + bval;
        if constexpr (OM == 1) {
          ((unsigned short*)Cv)[coff + (long long)row * ldc + col] = f2bf(val);
        } else if constexpr (OM == 2) {
          ((unsigned short*)Cv)[coff + (long long)col * ldc + row] = f2bf(val);
        } else {
          ((float*)Cv)[coff + (long long)row * ldc + col] = val;
        }
      }
    }
  }
}

// ================= 256x256 stage-early counted-vmcnt GEMM =================
// C[M,N] = A[M,K] * Bt[N,K]^T, bf16 in, tile 256x256, BK=64, 512 threads
// (8 waves, 2M x 4N), LDS 128 KiB double-buffered, conflict-free XOR swizzle.
// Schedule: at top of tile k, issue ALL 8 stages for tile k+1 (full-tile
// latency cover), vmcnt(8) waits only tile k's loads (landed long ago),
// ONE barrier, then free-running quadrant compute (no intra-tile barriers;
// waves drift, MFMA/LDS overlap across the 2 waves/SIMD), end barrier.
// XCD-chunked block swizzle: contiguous linear-bid chunk per XCD.
#define STAGE_A8(nb, koff, i)                                  \
  gload_lds16(gaL + (long long)((i) * 8) * lda + (koff) + scol, \
              &lA[nb][(wid * 32 + (i) * 8) * 64])
#define STAGE_B8(nb, koff, i)                                  \
  gload_lds16(gbL + (long long)((i) * 8) * ldb + (koff) + scol, \
              &lB[nb][(wid * 32 + (i) * 8) * 64])

template <int OM>
__global__ __launch_bounds__(512, 2) void k_gemm8p(
    const unsigned short* __restrict__ A, const unsigned short* __restrict__ Bt,
    void* __restrict__ Cv, const float* __restrict__ bias,
    const float* __restrict__ rAdd, const float* __restrict__ cAdd,
    int K, int lda, int ldb, int ldc,
    int azs, int azm, long long azr,
    int bzs, int bzm, long long bzr,
    int czs, long long czr, int czm, int czc,
    int biasm, int bstr, int rstr, float scale, int kzm, int kzr) {
  __shared__ unsigned short lA[2][256 * 64];
  __shared__ unsigned short lB[2][256 * 64];
  const int tid = threadIdx.x, wid = tid >> 6, lane = tid & 63;
  const int wm = wid >> 2, wn = wid & 3;

  // XCD-chunked bijective block swizzle (nwg is a multiple of 8 for all uses)
  const int gx = gridDim.x, gy = gridDim.y;
  const int nwg = gx * gy * gridDim.z;
  const int bidL = blockIdx.x + gx * (blockIdx.y + gy * blockIdx.z);
  const int q8 = nwg >> 3;
  const int idx = (bidL & 7) * q8 + (bidL >> 3);
  const int bx = idx % gx;
  const int rem = idx / gx;
  const int by = rem % gy;
  const int z = rem / gy;

  const int m0 = by * 256, n0 = bx * 256;
  const int kstart = (z & kzm) * kzr;
  const unsigned short* Az = A + (long long)((z >> azs) & azm) * azr + (long long)m0 * lda + kstart;
  const unsigned short* Bz = Bt + (long long)((z >> bzs) & bzm) * bzr + (long long)n0 * ldb + kstart;

  // staging: wave wid covers rows [wid*32, +32) of A and of B (4 insts each);
  // per-lane source col quad = (l&7) ^ (l>>3)  (the read-side involution)
  const int scol = (((lane & 7) ^ ((lane >> 3) & 7)) << 3);
  const unsigned short* gaL = Az + (long long)(wid * 32 + (lane >> 3)) * lda;
  const unsigned short* gbL = Bz + (long long)(wid * 32 + (lane >> 3)) * ldb;

  // fragment read addressing: row = ..+fr, col = (kq + t*32) ^ ((fr&7)<<3)
  const int fr = lane & 15, kq = (lane >> 4) * 8;
  const int fsw = (fr & 7) << 3;
  const int rc0 = kq ^ fsw;         // kstep 0 col
  const int rc1 = (32 + kq) ^ fsw;  // kstep 1 col
  const int aBase = (wm * 128 + fr) * 64;
  const int bBase = (wn * 64 + fr) * 64;

  f32x4 acc[8][4] = {};
  b16x8 afr[4][2], bfr[4][2];
  const int NT = K >> 6;

  // prologue: stage tile 0 into buf 0
#pragma unroll
  for (int i = 0; i < 4; ++i) { STAGE_A8(0, 0, i); STAGE_B8(0, 0, i); }

  for (int kt = 0; kt < NT; ++kt) {
    const int cur = kt & 1, nb = cur ^ 1;
    if (kt + 1 < NT) {
      const int ko = (kt + 1) << 6;
      // stage ALL of tile kt+1 now: full-tile latency cover
#pragma unroll
      for (int i = 0; i < 4; ++i) { STAGE_A8(nb, ko, i); STAGE_B8(nb, ko, i); }
      asm volatile("s_waitcnt vmcnt(8)" ::: "memory");  // tile kt's 8 done
    } else {
      asm volatile("s_waitcnt vmcnt(0)" ::: "memory");
    }
    __builtin_amdgcn_s_barrier();
    __builtin_amdgcn_sched_barrier(0);  // keep ds_reads below the barrier

    // ---- free-running compute on buf[cur]: 4 quadrants, no barriers ----
    // Q0: (Mlo x Nlo)
#pragma unroll
    for (int i = 0; i < 4; ++i) {
      afr[i][0] = *(const b16x8*)&lA[cur][aBase + i * 1024 + rc0];
      afr[i][1] = *(const b16x8*)&lA[cur][aBase + i * 1024 + rc1];
    }
#pragma unroll
    for (int j = 0; j < 2; ++j) {
      bfr[j][0] = *(const b16x8*)&lB[cur][bBase + j * 1024 + rc0];
      bfr[j][1] = *(const b16x8*)&lB[cur][bBase + j * 1024 + rc1];
    }
    __builtin_amdgcn_s_setprio(1);
#pragma unroll
    for (int t = 0; t < 2; ++t)
#pragma unroll
      for (int i = 0; i < 4; ++i)
#pragma unroll
        for (int j = 0; j < 2; ++j)
          acc[i][j] = __builtin_amdgcn_mfma_f32_16x16x32_bf16(afr[i][t], bfr[j][t], acc[i][j], 0, 0, 0);
    __builtin_amdgcn_s_setprio(0);
    // Q1: (Mlo x Nhi)
#pragma unroll
    for (int j = 2; j < 4; ++j) {
      bfr[j][0] = *(const b16x8*)&lB[cur][bBase + j * 1024 + rc0];
      bfr[j][1] = *(const b16x8*)&lB[cur][bBase + j * 1024 + rc1];
    }
    __builtin_amdgcn_s_setprio(1);
#pragma unroll
    for (int t = 0; t < 2; ++t)
#pragma unroll
      for (int i = 0; i < 4; ++i)
#pragma unroll
        for (int j = 2; j < 4; ++j)
          acc[i][j] = __builtin_amdgcn_mfma_f32_16x16x32_bf16(afr[i][t], bfr[j][t], acc[i][j], 0, 0, 0);
    __builtin_amdgcn_s_setprio(0);
    // Q2: (Mhi x Nlo)
#pragma unroll
    for (int i = 0; i < 4; ++i) {
      afr[i][0] = *(const b16x8*)&lA[cur][aBase + (i + 4) * 1024 + rc0];
      afr[i][1] = *(const b16x8*)&lA[cur][aBase + (i + 4) * 1024 + rc1];
    }
    __builtin_amdgcn_s_setprio(1);
#pragma unroll
    for (int t = 0; t < 2; ++t)
#pragma unroll
      for (int i = 0; i < 4; ++i)
#pragma unroll
        for (int j = 0; j < 2; ++j)
          acc[i + 4][j] = __builtin_amdgcn_mfma_f32_16x16x32_bf16(afr[i][t], bfr[j][t], acc[i + 4][j], 0, 0, 0);
    __builtin_amdgcn_s_setprio(0);
    // Q3: (Mhi x Nhi)
    __builtin_amdgcn_s_setprio(1);
#pragma unroll
    for (int t = 0; t < 2; ++t)
#pragma unroll
      for (int i = 0; i < 4; ++i)
#pragma unroll
        for (int j = 2; j < 4; ++j)
          acc[i + 4][j] = __builtin_amdgcn_mfma_f32_16x16x32_bf16(afr[i][t], bfr[j][t], acc[i + 4][j], 0, 0, 0);
    __builtin_amdgcn_s_setprio(0);

    __builtin_amdgcn_s_barrier();  // end of tile: buf[cur] free for next-iter staging
  }

  const long long coff = (long long)(z >> czs) * czr + (long long)(z & czm) * czc;
  const long long zr = (long long)z * rstr;
  const int rr = (lane >> 4) * 4;
#pragma unroll
  for (int j = 0; j < 4; ++j) {
    const int col = n0 + wn * 64 + j * 16 + (lane & 15);
    const float bval = bias ? bias[(long long)(z & biasm) * bstr + col] : 0.f;
    const float ca = cAdd ? cAdd[zr + col] : 0.f;
#pragma unroll
    for (int i = 0; i < 8; ++i) {
#pragma unroll
      for (int r = 0; r < 4; ++r) {
        const int row = m0 + wm * 128 + i * 16 + rr + r;
        const float ra = rAdd ? rAdd[zr + row] : 0.f;
        const float val = (acc[i][j][r] + ra + ca) * scale + bval;
        if constexpr (OM == 1) {
          ((unsigned short*)Cv)[coff + (long long)row * ldc + col] = f2bf(val);
        } else if constexpr (OM == 2) {
          ((unsigned short*)Cv)[coff + (long long)col * ldc + row] = f2bf(val);
        } else {
          ((float*)Cv)[coff + (long long)row * ldc + col] = val;
        }
      }
    }
  }
}

// ---------------- out = sum of 4 f32 partials + bias(per 512 cols) ----------------
__global__ __launch_bounds__(256) void k_reduce4(const float* __restrict__ p,
                                                 const float* __restrict__ bo,
                                                 float* __restrict__ out) {
  const long long i = (long long)blockIdx.x * 256 + threadIdx.x;
  const float4* p4 = (const float4*)p;
  float4 a = p4[i], b = p4[i + 1048576], c = p4[i + 2097152], d = p4[i + 3145728];
  const float4 bb = ((const float4*)bo)[i & 127];
  float4 o;
  o.x = a.x + b.x + c.x + d.x + bb.x;
  o.y = a.y + b.y + c.y + d.y + bb.y;
  o.z = a.z + b.z + c.z + d.z + bb.z;
  o.w = a.w + b.w + c.w + d.w + bb.w;
  ((float4*)out)[i] = o;
}

extern "C" void kernel_launch(void* const* d_in, const int* in_sizes, int n_in,
                              void* d_out, int out_size, void* d_ws, size_t ws_size,
                              hipStream_t stream) {
  const float* in1 = (const float*)d_in[0];
  const float* in2 = (const float*)d_in[1];
  const float* in3 = (const float*)d_in[2];
  const float* Wq = (const float*)d_in[3];
  const float* bq = (const float*)d_in[4];
  const float* Wk = (const float*)d_in[5];
  const float* bk = (const float*)d_in[6];
  const float* Wv = (const float*)d_in[7];
  const float* bv = (const float*)d_in[8];
  const float* Wo = (const float*)d_in[9];
  const float* bo = (const float*)d_in[10];

  const long long MB = 1024 * 1024;
  typedef unsigned short us;
  unsigned char* w = (unsigned char*)d_ws;
  us* in2b = (us*)(w);                 // 8 MB
  us* Tbuf = (us*)(w + 8 * MB);        // 64 MB (T, then concat per-chunk)
  us* Vt = (us*)(w + 72 * MB);         // 64 MB (then out-proj partials)
  us* wvt = (us*)(w + 136 * MB);       // 4 MB
  us* wot = (us*)(w + 140 * MB);       // 4 MB
  us* scb = (us*)(w + 144 * MB);       // 64 MB (scores/P bf16, in-place)
  us* in1b = (us*)(w + 208 * MB);      // 8 MB
  us* in3b = (us*)(w + 216 * MB);      // 8 MB
  us* wqb = (us*)(w + 224 * MB);       // 4 MB
  us* wkb = (us*)(w + 228 * MB);       // 4 MB
  us* Gt = (us*)(w + 232 * MB);        // 4 MB
  float* rt = (float*)(w + 236 * MB);  // 256 KB
  float* ct = (float*)(w + 236 * MB + (256 << 10));
  float* ubuf = (float*)(w + 237 * MB);
  float* vbuf = (float*)(w + 237 * MB + (16 << 10));
  float* cbuf = (float*)(w + 237 * MB + (32 << 10));
  float* partials = (float*)(w + 72 * MB);  // 64 MB over Vt (dead by then)
  if ((long long)ws_size < 238 * MB) return;

  const float iscale = 0.04419417382415922f;  // 1/sqrt(512)
  const long long SD = 1024 * 512;            // 524288

  // conversions / transposes
  k_conv_bf16<<<4096, 256, 0, stream>>>(in1, in1b, 1048576);
  k_conv_bf16<<<4096, 256, 0, stream>>>(in2, in2b, 1048576);
  k_conv_bf16<<<4096, 256, 0, stream>>>(in3, in3b, 1048576);
  k_conv_bf16<<<2048, 256, 0, stream>>>(Wq, wqb, 524288);
  k_conv_bf16<<<2048, 256, 0, stream>>>(Wk, wkb, 524288);
  k_transpose_bf16<<<dim3(16, 16, 8), dim3(32, 8), 0, stream>>>(Wv, wvt, 512, 512);
  k_transpose_bf16<<<dim3(16, 128, 1), dim3(32, 8), 0, stream>>>(Wo, wot, 4096, 512);

  // bias cross-terms
  k_uv<<<dim3(1024, 2), 256, 0, stream>>>(Wq, bk, Wk, bq, ubuf, vbuf);
  k_bdot<<<1, 512, 0, stream>>>(bq, bk, cbuf);
  k_rtct<<<dim3(8192, 2), 256, 0, stream>>>(in1, in2, ubuf, vbuf, cbuf, rt, ct);

  // Gt[h] = Wk[h] Wq[h]^T  (small; old kernel)
  k_gemm_bt<1><<<dim3(4, 4, 8), 256, 0, stream>>>(
      wkb, wqb, Gt, nullptr, nullptr, nullptr, 512, 512, 512, 512,
      0, 7, 262144LL, 0, 7, 262144LL, 0, 262144LL, 0, 0, 0, 0, 0, 1.f);

  // T[z=b*8+h] = X1[b] G[h]   [64][1024][512] bf16
  k_gemm8p<1><<<dim3(2, 4, 64), 512, 0, stream>>>(
      in1b, Gt, Tbuf, nullptr, nullptr, nullptr, 512, 512, 512, 512,
      3, 7, SD, 0, 7, 262144LL, 0, SD, 0, 0, 0, 0, 0, 1.f, 0, 0);

  // V-proj transposed: Vt[z][e][s]  [64][512][1024] bf16, +bv
  k_gemm8p<2><<<dim3(2, 4, 64), 512, 0, stream>>>(
      in3b, wvt, Vt, bv, nullptr, nullptr, 512, 512, 512, 1024,
      3, 7, SD, 0, 7, 262144LL, 0, SD, 0, 0, 7, 512, 0, 1.f, 0, 0);

  // attention in 2 chunks of 4 batches (32 heads each)
  for (int c = 0; c < 2; ++c) {
    // scores[zz][i][j] = (T X2^T + rt + ct) * iscale -> bf16
    k_gemm8p<1><<<dim3(4, 4, 32), 512, 0, stream>>>(
        Tbuf + (long long)c * 32 * SD, in2b + (long long)c * 4 * SD, scb, nullptr,
        rt + c * 32768, ct + c * 32768, 512, 512, 512, 1024,
        0, 31, SD, 3, 3, SD, 0, 1048576LL, 0, 0, 0, 0, 1024, iscale, 0, 0);
    k_softmax_bf16<<<8192, 256, 0, stream>>>(scb);
    // heads -> concat[(c*4+b')*1024 + i][h*512 + e]
    k_gemm8p<1><<<dim3(2, 4, 32), 512, 0, stream>>>(
        scb, Vt + (long long)c * 32 * SD, Tbuf + (long long)c * 16777216LL, nullptr,
        nullptr, nullptr, 1024, 1024, 1024, 4096,
        0, 31, 1048576LL, 0, 31, SD, 3, 4194304LL, 7, 512, 0, 0, 0, 1.f, 0, 0);
  }

  // out-proj split-K=4: partials[ks] = concat[:, ks*1024:+1024] @ wot[:, same]^T
  k_gemm8p<0><<<dim3(2, 32, 4), 512, 0, stream>>>(
      Tbuf, wot, partials, nullptr, nullptr, nullptr, 1024, 4096, 4096, 512,
      0, 0, 0, 0, 0, 0, 0, 4194304LL, 0, 0, 0, 0, 0, 1.f, 3, 1024);
  k_reduce4<<<4096, 256, 0, stream>>>(partials, bo, (float*)d_out);
}

// Round 6
// 481.462 us; speedup vs baseline: 1.5176x; 1.2274x over previous
//
#include <hip/hip_runtime.h>
#include <hip/hip_bf16.h>

#define DEV static __device__ __forceinline__

typedef float f32x4 __attribute__((ext_vector_type(4)));
typedef __bf16 b16x8 __attribute__((ext_vector_type(8)));

DEV unsigned short f2bf(float f) {
  union { __hip_bfloat16 h; unsigned short u; } cv;
  cv.h = __float2bfloat16(f);
  return cv.u;
}

DEV void gload_lds16(const unsigned short* g, unsigned short* l) {
  __builtin_amdgcn_global_load_lds(
      (__attribute__((address_space(1))) void*)g,
      (__attribute__((address_space(3))) void*)l, 16, 0, 0);
}

// ---------------- f32 -> bf16 elementwise ----------------
__global__ __launch_bounds__(256) void k_conv_bf16(const float* __restrict__ src,
                                                   unsigned short* __restrict__ dst,
                                                   long long n4) {
  long long i = (long long)blockIdx.x * 256 + threadIdx.x;
  if (i >= n4) return;
  const float4 v = ((const float4*)src)[i];
  ushort4 o;
  o.x = f2bf(v.x); o.y = f2bf(v.y); o.z = f2bf(v.z); o.w = f2bf(v.w);
  ((ushort4*)dst)[i] = o;
}

// ---------------- f32 [z][R][C] -> bf16 [z][C][R] ----------------
__global__ __launch_bounds__(256) void k_transpose_bf16(const float* __restrict__ src,
                                                        unsigned short* __restrict__ dst,
                                                        int R, int C) {
  __shared__ float t[32][33];
  const long long zo = (long long)blockIdx.z * R * C;
  const int c0 = blockIdx.x * 32, r0 = blockIdx.y * 32;
  const int tx = threadIdx.x, ty = threadIdx.y;
#pragma unroll
  for (int i = 0; i < 4; ++i)
    t[ty + i * 8][tx] = src[zo + (long long)(r0 + ty + i * 8) * C + c0 + tx];
  __syncthreads();
#pragma unroll
  for (int i = 0; i < 4; ++i)
    dst[zo + (long long)(c0 + ty + i * 8) * R + r0 + tx] = f2bf(t[tx][ty + i * 8]);
}

// ---------------- u[h,d]=sum_e Wq[h,d,e]*bk[h,e] (sel0) / v from Wk,bq (sel1) ----------------
__global__ __launch_bounds__(256) void k_uv(const float* __restrict__ Wq, const float* __restrict__ bk,
                                            const float* __restrict__ Wk, const float* __restrict__ bq,
                                            float* __restrict__ u, float* __restrict__ v) {
  const int sel = blockIdx.y;
  const float* W = sel ? Wk : Wq;
  const float* bb = sel ? bq : bk;
  float* dst = sel ? v : u;
  const int wave = threadIdx.x >> 6, lane = threadIdx.x & 63;
  const int idx = blockIdx.x * 4 + wave;
  const int h = idx >> 9, d = idx & 511;
  const float* wr = W + ((long long)h * 512 + d) * 512 + lane * 8;
  const float* br = bb + h * 512 + lane * 8;
  float s = 0.f;
#pragma unroll
  for (int k = 0; k < 8; ++k) s += wr[k] * br[k];
#pragma unroll
  for (int off = 32; off; off >>= 1) s += __shfl_xor(s, off);
  if (lane == 0) dst[h * 512 + d] = s;
}

// ---------------- c[h] = bq[h].bk[h] ----------------
__global__ __launch_bounds__(512) void k_bdot(const float* __restrict__ bq,
                                              const float* __restrict__ bk,
                                              float* __restrict__ c) {
  const int wave = threadIdx.x >> 6, lane = threadIdx.x & 63;
  const float* a = bq + wave * 512 + lane * 8;
  const float* b = bk + wave * 512 + lane * 8;
  float s = 0.f;
#pragma unroll
  for (int k = 0; k < 8; ++k) s += a[k] * b[k];
#pragma unroll
  for (int off = 32; off; off >>= 1) s += __shfl_xor(s, off);
  if (lane == 0) c[wave] = s;
}

// ---------------- rt[b*8+h][i] = in1[b,i,:].u[h,:] + c[h]; ct from in2,v ----------------
__global__ __launch_bounds__(256) void k_rtct(const float* __restrict__ in1, const float* __restrict__ in2,
                                              const float* __restrict__ u, const float* __restrict__ v,
                                              const float* __restrict__ cbuf,
                                              float* __restrict__ rt, float* __restrict__ ct) {
  const int sel = blockIdx.y;
  const float* src = sel ? in2 : in1;
  const float* vec = sel ? v : u;
  float* dst = sel ? ct : rt;
  const int row = blockIdx.x;
  __shared__ float x[512];
  const float* p = src + (long long)row * 512;
  x[threadIdx.x] = p[threadIdx.x];
  x[threadIdx.x + 256] = p[threadIdx.x + 256];
  __syncthreads();
  const int wave = threadIdx.x >> 6, lane = threadIdx.x & 63;
  const int b = row >> 10, i = row & 1023;
#pragma unroll
  for (int t = 0; t < 2; ++t) {
    const int h = wave * 2 + t;
    const float* wv = vec + h * 512;
    float s = 0.f;
#pragma unroll
    for (int k = 0; k < 8; ++k) s += x[lane + k * 64] * wv[lane + k * 64];
#pragma unroll
    for (int off = 32; off; off >>= 1) s += __shfl_xor(s, off);
    if (lane == 0)
      dst[((long long)(b * 8 + h)) * 1024 + i] = s + (sel ? 0.f : cbuf[h]);
  }
}

// ---------------- in-place row softmax over 1024 bf16, one wave per row ----------------
__global__ __launch_bounds__(256) void k_softmax_bf16(unsigned short* __restrict__ P) {
  const int wave = threadIdx.x >> 6, lane = threadIdx.x & 63;
  unsigned short* p = P + ((long long)blockIdx.x * 4 + wave) * 1024 + lane * 16;
  const b16x8 v0 = *(const b16x8*)p;
  const b16x8 v1 = *(const b16x8*)(p + 8);
  float f[16];
#pragma unroll
  for (int j = 0; j < 8; ++j) { f[j] = (float)v0[j]; f[8 + j] = (float)v1[j]; }
  float mx = f[0];
#pragma unroll
  for (int j = 1; j < 16; ++j) mx = fmaxf(mx, f[j]);
#pragma unroll
  for (int off = 32; off; off >>= 1) mx = fmaxf(mx, __shfl_xor(mx, off));
  float sum = 0.f;
#pragma unroll
  for (int j = 0; j < 16; ++j) { f[j] = __expf(f[j] - mx); sum += f[j]; }
#pragma unroll
  for (int off = 32; off; off >>= 1) sum += __shfl_xor(sum, off);
  const float inv = 1.f / sum;
  b16x8 o0, o1;
#pragma unroll
  for (int j = 0; j < 8; ++j) { o0[j] = (__bf16)(f[j] * inv); o1[j] = (__bf16)(f[8 + j] * inv); }
  *(b16x8*)p = o0;
  *(b16x8*)(p + 8) = o1;
}

// ---------------- old 128x128 GEMM (kept for the small Gt GEMM) ----------------
template <int OM>
__global__ __launch_bounds__(256) void k_gemm_bt(
    const unsigned short* __restrict__ A, const unsigned short* __restrict__ Bt,
    void* __restrict__ Cv, const float* __restrict__ bias,
    const float* __restrict__ rAdd, const float* __restrict__ cAdd,
    int K, int lda, int ldb, int ldc,
    int azs, int azm, long long azr,
    int bzs, int bzm, long long bzr,
    int czs, long long czr, int czm, int czc,
    int biasm, int bstr, int rstr, float scale) {
  __shared__ unsigned short lA[128 * 64];
  __shared__ unsigned short lB[128 * 64];
  const int tid = threadIdx.x, wave = tid >> 6, lane = tid & 63;
  const int z = blockIdx.z;
  const int m0 = blockIdx.y * 128, n0 = blockIdx.x * 128;
  const unsigned short* Az = A + (long long)((z >> azs) & azm) * azr + (long long)m0 * lda;
  const unsigned short* Bz = Bt + (long long)((z >> bzs) & bzm) * bzr + (long long)n0 * ldb;

  const int srow = wave * 32 + (lane >> 3);
  const int scol = (lane & 7) * 8;
  const unsigned short* ga = Az + (long long)srow * lda + scol;
  const unsigned short* gb = Bz + (long long)srow * ldb + scol;
  unsigned short* laBase = &lA[(wave * 32) * 64];
  unsigned short* lbBase = &lB[(wave * 32) * 64];

  f32x4 acc[4][4] = {};
  const int wr = (wave >> 1) * 64, wc = (wave & 1) * 64;
  const int fr = lane & 15, kq = (lane >> 4) * 8;

  for (int k0 = 0; k0 < K; k0 += 64) {
#pragma unroll
    for (int i = 0; i < 4; ++i) {
      gload_lds16(ga + (long long)(i * 8) * lda + k0, laBase + (i * 8) * 64);
      gload_lds16(gb + (long long)(i * 8) * ldb + k0, lbBase + (i * 8) * 64);
    }
    __syncthreads();
#pragma unroll
    for (int kk = 0; kk < 64; kk += 32) {
      b16x8 af[4], bf[4];
#pragma unroll
      for (int i = 0; i < 4; ++i)
        af[i] = *(const b16x8*)&lA[(wr + i * 16 + fr) * 64 + kk + kq];
#pragma unroll
      for (int j = 0; j < 4; ++j)
        bf[j] = *(const b16x8*)&lB[(wc + j * 16 + fr) * 64 + kk + kq];
#pragma unroll
      for (int i = 0; i < 4; ++i)
#pragma unroll
        for (int j = 0; j < 4; ++j)
          acc[i][j] = __builtin_amdgcn_mfma_f32_16x16x32_bf16(af[i], bf[j], acc[i][j], 0, 0, 0);
    }
    __syncthreads();
  }

  const long long coff = (long long)(z >> czs) * czr + (long long)(z & czm) * czc;
  const long long zr = (long long)z * rstr;
  const int rr = (lane >> 4) * 4;
#pragma unroll
  for (int j = 0; j < 4; ++j) {
    const int col = n0 + wc + j * 16 + fr;
    const float bval = bias ? bias[(long long)(z & biasm) * bstr + col] : 0.f;
    const float ca = cAdd ? cAdd[zr + col] : 0.f;
#pragma unroll
    for (int i = 0; i < 4; ++i) {
#pragma unroll
      for (int r = 0; r < 4; ++r) {
        const int row = m0 + wr + i * 16 + rr + r;
        const float ra = rAdd ? rAdd[zr + row] : 0.f;
        const float val = (acc[i][j][r] + ra + ca) * scale + bval;
        if constexpr (OM == 1) {
          ((unsigned short*)Cv)[coff + (long long)row * ldc + col] = f2bf(val);
        } else if constexpr (OM == 2) {
          ((unsigned short*)Cv)[coff + (long long)col * ldc + row] = f2bf(val);
        } else {
          ((float*)Cv)[coff + (long long)row * ldc + col] = val;
        }
      }
    }
  }
}

// ================= 256x256 stage-early GEMM, LDS-coalesced epilogue =========
// K-loop identical to R5 (stage-all-early, vmcnt(8), free-running quadrants).
// NEW: epilogue stages the 256x256 output tile into the (now dead) 128 KiB
// LDS in output-layout order (16B-quad XOR swizzle for banks), then linearly
// copies LDS->global as dwordx4 (1 KiB/wave-instr) — replaces 4096 scattered
// 2-byte stores per block with 128 coalesced 16B-lane stores.
#define STAGE_A8(nb, koff, i)                                  \
  gload_lds16(gaL + (long long)((i) * 8) * lda + (koff) + scol, \
              &sh[nb][(wid * 32 + (i) * 8) * 64])
#define STAGE_B8(nb, koff, i)                                  \
  gload_lds16(gbL + (long long)((i) * 8) * ldb + (koff) + scol, \
              &sh[2 + (nb)][(wid * 32 + (i) * 8) * 64])

template <int OM>
__global__ __launch_bounds__(512, 2) void k_gemm8p(
    const unsigned short* __restrict__ A, const unsigned short* __restrict__ Bt,
    void* __restrict__ Cv, const float* __restrict__ bias,
    const float* __restrict__ rAdd, const float* __restrict__ cAdd,
    int K, int lda, int ldb, int ldc,
    int azs, int azm, long long azr,
    int bzs, int bzm, long long bzr,
    int czs, long long czr, int czm, int czc,
    int biasm, int bstr, int rstr, float scale, int kzm, int kzr) {
  __shared__ unsigned short sh[4][256 * 64];  // sh[0..1]=A dbuf, sh[2..3]=B dbuf
  const int tid = threadIdx.x, wid = tid >> 6, lane = tid & 63;
  const int wm = wid >> 2, wn = wid & 3;

  // XCD-chunked bijective block swizzle (nwg is a multiple of 8 for all uses)
  const int gx = gridDim.x, gy = gridDim.y;
  const int nwg = gx * gy * gridDim.z;
  const int bidL = blockIdx.x + gx * (blockIdx.y + gy * blockIdx.z);
  const int q8 = nwg >> 3;
  const int idx = (bidL & 7) * q8 + (bidL >> 3);
  const int bx = idx % gx;
  const int rem = idx / gx;
  const int by = rem % gy;
  const int z = rem / gy;

  const int m0 = by * 256, n0 = bx * 256;
  const int kstart = (z & kzm) * kzr;
  const unsigned short* Az = A + (long long)((z >> azs) & azm) * azr + (long long)m0 * lda + kstart;
  const unsigned short* Bz = Bt + (long long)((z >> bzs) & bzm) * bzr + (long long)n0 * ldb + kstart;

  const int scol = (((lane & 7) ^ ((lane >> 3) & 7)) << 3);
  const unsigned short* gaL = Az + (long long)(wid * 32 + (lane >> 3)) * lda;
  const unsigned short* gbL = Bz + (long long)(wid * 32 + (lane >> 3)) * ldb;

  const int fr = lane & 15, kq = (lane >> 4) * 8;
  const int fsw = (fr & 7) << 3;
  const int rc0 = kq ^ fsw;
  const int rc1 = (32 + kq) ^ fsw;
  const int aBase = (wm * 128 + fr) * 64;
  const int bBase = (wn * 64 + fr) * 64;

  f32x4 acc[8][4] = {};
  b16x8 afr[4][2], bfr[4][2];
  const int NT = K >> 6;

#pragma unroll
  for (int i = 0; i < 4; ++i) { STAGE_A8(0, 0, i); STAGE_B8(0, 0, i); }

  for (int kt = 0; kt < NT; ++kt) {
    const int cur = kt & 1, nb = cur ^ 1;
    if (kt + 1 < NT) {
      const int ko = (kt + 1) << 6;
#pragma unroll
      for (int i = 0; i < 4; ++i) { STAGE_A8(nb, ko, i); STAGE_B8(nb, ko, i); }
      asm volatile("s_waitcnt vmcnt(8)" ::: "memory");
    } else {
      asm volatile("s_waitcnt vmcnt(0)" ::: "memory");
    }
    __builtin_amdgcn_s_barrier();
    __builtin_amdgcn_sched_barrier(0);

    // Q0
#pragma unroll
    for (int i = 0; i < 4; ++i) {
      afr[i][0] = *(const b16x8*)&sh[cur][aBase + i * 1024 + rc0];
      afr[i][1] = *(const b16x8*)&sh[cur][aBase + i * 1024 + rc1];
    }
#pragma unroll
    for (int j = 0; j < 2; ++j) {
      bfr[j][0] = *(const b16x8*)&sh[2 + cur][bBase + j * 1024 + rc0];
      bfr[j][1] = *(const b16x8*)&sh[2 + cur][bBase + j * 1024 + rc1];
    }
    __builtin_amdgcn_s_setprio(1);
#pragma unroll
    for (int t = 0; t < 2; ++t)
#pragma unroll
      for (int i = 0; i < 4; ++i)
#pragma unroll
        for (int j = 0; j < 2; ++j)
          acc[i][j] = __builtin_amdgcn_mfma_f32_16x16x32_bf16(afr[i][t], bfr[j][t], acc[i][j], 0, 0, 0);
    __builtin_amdgcn_s_setprio(0);
    // Q1
#pragma unroll
    for (int j = 2; j < 4; ++j) {
      bfr[j][0] = *(const b16x8*)&sh[2 + cur][bBase + j * 1024 + rc0];
      bfr[j][1] = *(const b16x8*)&sh[2 + cur][bBase + j * 1024 + rc1];
    }
    __builtin_amdgcn_s_setprio(1);
#pragma unroll
    for (int t = 0; t < 2; ++t)
#pragma unroll
      for (int i = 0; i < 4; ++i)
#pragma unroll
        for (int j = 2; j < 4; ++j)
          acc[i][j] = __builtin_amdgcn_mfma_f32_16x16x32_bf16(afr[i][t], bfr[j][t], acc[i][j], 0, 0, 0);
    __builtin_amdgcn_s_setprio(0);
    // Q2
#pragma unroll
    for (int i = 0; i < 4; ++i) {
      afr[i][0] = *(const b16x8*)&sh[cur][aBase + (i + 4) * 1024 + rc0];
      afr[i][1] = *(const b16x8*)&sh[cur][aBase + (i + 4) * 1024 + rc1];
    }
    __builtin_amdgcn_s_setprio(1);
#pragma unroll
    for (int t = 0; t < 2; ++t)
#pragma unroll
      for (int i = 0; i < 4; ++i)
#pragma unroll
        for (int j = 0; j < 2; ++j)
          acc[i + 4][j] = __builtin_amdgcn_mfma_f32_16x16x32_bf16(afr[i][t], bfr[j][t], acc[i + 4][j], 0, 0, 0);
    __builtin_amdgcn_s_setprio(0);
    // Q3
    __builtin_amdgcn_s_setprio(1);
#pragma unroll
    for (int t = 0; t < 2; ++t)
#pragma unroll
      for (int i = 0; i < 4; ++i)
#pragma unroll
        for (int j = 2; j < 4; ++j)
          acc[i + 4][j] = __builtin_amdgcn_mfma_f32_16x16x32_bf16(afr[i][t], bfr[j][t], acc[i + 4][j], 0, 0, 0);
    __builtin_amdgcn_s_setprio(0);

    __builtin_amdgcn_s_barrier();
  }

  // ---------------- LDS-coalesced epilogue ----------------
  const long long coff = (long long)(z >> czs) * czr + (long long)(z & czm) * czc;
  const long long zr = (long long)z * rstr;
  const int rr = (lane >> 4) * 4;
  unsigned short* flat = &sh[0][0];  // 128 KiB, dead after K-loop's final barrier

  if constexpr (OM == 1 || OM == 2) {
    // stage: output-layout coords (sR, sC); element col swizzled by 16B quad
#pragma unroll
    for (int j = 0; j < 4; ++j) {
      const int col = n0 + wn * 64 + j * 16 + fr;
      const float bval = bias ? bias[(long long)(z & biasm) * bstr + col] : 0.f;
      const float ca = cAdd ? cAdd[zr + col] : 0.f;
#pragma unroll
      for (int i = 0; i < 8; ++i) {
#pragma unroll
        for (int r = 0; r < 4; ++r) {
          const int row = m0 + wm * 128 + i * 16 + rr + r;
          const float ra = rAdd ? rAdd[zr + row] : 0.f;
          const float val = (acc[i][j][r] + ra + ca) * scale + bval;
          const int rowL = wm * 128 + i * 16 + rr + r;
          const int colL = wn * 64 + j * 16 + fr;
          const int sR = (OM == 2) ? colL : rowL;
          const int sC = (OM == 2) ? rowL : colL;
          flat[sR * 256 + (sC ^ ((sR & 7) << 3))] = f2bf(val);
        }
      }
    }
    __builtin_amdgcn_s_barrier();
    // readout: 16 iters x 512 threads x 16B = 128 KiB, coalesced
    const long long rbase = (OM == 2) ? (long long)n0 : (long long)m0;
    const long long cbase = (OM == 2) ? (long long)m0 : (long long)n0;
    unsigned short* Cb = (unsigned short*)Cv;
#pragma unroll
    for (int it = 0; it < 16; ++it) {
      const int t = it * 512 + tid;
      const int R = t >> 5;
      const int Cq = t & 31;
      const int q = Cq ^ (R & 7);
      const b16x8 v = *(const b16x8*)&flat[R * 256 + q * 8];
      *(b16x8*)(Cb + coff + (rbase + R) * ldc + cbase + Cq * 8) = v;
    }
  } else {
    // f32 out in two 128-row halves (128 KiB each)
    float* fflat = (float*)flat;
    float* Cf = (float*)Cv;
#pragma unroll
    for (int half = 0; half < 2; ++half) {
      if (wm == half) {
#pragma unroll
        for (int j = 0; j < 4; ++j) {
          const int col = n0 + wn * 64 + j * 16 + fr;
          const float bval = bias ? bias[(long long)(z & biasm) * bstr + col] : 0.f;
          const float ca = cAdd ? cAdd[zr + col] : 0.f;
#pragma unroll
          for (int i = 0; i < 8; ++i) {
#pragma unroll
            for (int r = 0; r < 4; ++r) {
              const int row = m0 + wm * 128 + i * 16 + rr + r;
              const float ra = rAdd ? rAdd[zr + row] : 0.f;
              const float val = (acc[i][j][r] + ra + ca) * scale + bval;
              const int Rl = i * 16 + rr + r;  // 0..127
              const int Cl = wn * 64 + j * 16 + fr;
              fflat[Rl * 256 + (Cl ^ ((Rl & 7) << 2))] = val;
            }
          }
        }
      }
      __builtin_amdgcn_s_barrier();
#pragma unroll
      for (int it = 0; it < 16; ++it) {
        const int t = it * 512 + tid;
        const int R = t >> 6;        // 0..127
        const int Cq = t & 63;       // 16B chunk (4 f32)
        const int q = Cq ^ (R & 7);
        const float4 v = *(const float4*)&fflat[R * 256 + q * 4];
        *(float4*)(Cf + coff + (long long)(m0 + half * 128 + R) * ldc + n0 + Cq * 4) = v;
      }
      __builtin_amdgcn_s_barrier();
    }
  }
}

// ---------------- out = sum of 4 f32 partials + bias(per 512 cols) ----------------
__global__ __launch_bounds__(256) void k_reduce4(const float* __restrict__ p,
                                                 const float* __restrict__ bo,
                                                 float* __restrict__ out) {
  const long long i = (long long)blockIdx.x * 256 + threadIdx.x;
  const float4* p4 = (const float4*)p;
  float4 a = p4[i], b = p4[i + 1048576], c = p4[i + 2097152], d = p4[i + 3145728];
  const float4 bb = ((const float4*)bo)[i & 127];
  float4 o;
  o.x = a.x + b.x + c.x + d.x + bb.x;
  o.y = a.y + b.y + c.y + d.y + bb.y;
  o.z = a.z + b.z + c.z + d.z + bb.z;
  o.w = a.w + b.w + c.w + d.w + bb.w;
  ((float4*)out)[i] = o;
}

extern "C" void kernel_launch(void* const* d_in, const int* in_sizes, int n_in,
                              void* d_out, int out_size, void* d_ws, size_t ws_size,
                              hipStream_t stream) {
  const float* in1 = (const float*)d_in[0];
  const float* in2 = (const float*)d_in[1];
  const float* in3 = (const float*)d_in[2];
  const float* Wq = (const float*)d_in[3];
  const float* bq = (const float*)d_in[4];
  const float* Wk = (const float*)d_in[5];
  const float* bk = (const float*)d_in[6];
  const float* Wv = (const float*)d_in[7];
  const float* bv = (const float*)d_in[8];
  const float* Wo = (const float*)d_in[9];
  const float* bo = (const float*)d_in[10];

  const long long MB = 1024 * 1024;
  typedef unsigned short us;
  unsigned char* w = (unsigned char*)d_ws;
  us* in2b = (us*)(w);                 // 8 MB
  us* Tbuf = (us*)(w + 8 * MB);        // 64 MB (T, then concat per-chunk)
  us* Vt = (us*)(w + 72 * MB);         // 64 MB (then out-proj partials)
  us* wvt = (us*)(w + 136 * MB);       // 4 MB
  us* wot = (us*)(w + 140 * MB);       // 4 MB
  us* scb = (us*)(w + 144 * MB);       // 64 MB (scores/P bf16, in-place)
  us* in1b = (us*)(w + 208 * MB);      // 8 MB
  us* in3b = (us*)(w + 216 * MB);      // 8 MB
  us* wqb = (us*)(w + 224 * MB);       // 4 MB
  us* wkb = (us*)(w + 228 * MB);       // 4 MB
  us* Gt = (us*)(w + 232 * MB);        // 4 MB
  float* rt = (float*)(w + 236 * MB);  // 256 KB
  float* ct = (float*)(w + 236 * MB + (256 << 10));
  float* ubuf = (float*)(w + 237 * MB);
  float* vbuf = (float*)(w + 237 * MB + (16 << 10));
  float* cbuf = (float*)(w + 237 * MB + (32 << 10));
  float* partials = (float*)(w + 72 * MB);  // 64 MB over Vt (dead by then)
  if ((long long)ws_size < 238 * MB) return;

  const float iscale = 0.04419417382415922f;  // 1/sqrt(512)
  const long long SD = 1024 * 512;            // 524288

  // conversions / transposes
  k_conv_bf16<<<4096, 256, 0, stream>>>(in1, in1b, 1048576);
  k_conv_bf16<<<4096, 256, 0, stream>>>(in2, in2b, 1048576);
  k_conv_bf16<<<4096, 256, 0, stream>>>(in3, in3b, 1048576);
  k_conv_bf16<<<2048, 256, 0, stream>>>(Wq, wqb, 524288);
  k_conv_bf16<<<2048, 256, 0, stream>>>(Wk, wkb, 524288);
  k_transpose_bf16<<<dim3(16, 16, 8), dim3(32, 8), 0, stream>>>(Wv, wvt, 512, 512);
  k_transpose_bf16<<<dim3(16, 128, 1), dim3(32, 8), 0, stream>>>(Wo, wot, 4096, 512);

  // bias cross-terms
  k_uv<<<dim3(1024, 2), 256, 0, stream>>>(Wq, bk, Wk, bq, ubuf, vbuf);
  k_bdot<<<1, 512, 0, stream>>>(bq, bk, cbuf);
  k_rtct<<<dim3(8192, 2), 256, 0, stream>>>(in1, in2, ubuf, vbuf, cbuf, rt, ct);

  // Gt[h] = Wk[h] Wq[h]^T  (small; old kernel)
  k_gemm_bt<1><<<dim3(4, 4, 8), 256, 0, stream>>>(
      wkb, wqb, Gt, nullptr, nullptr, nullptr, 512, 512, 512, 512,
      0, 7, 262144LL, 0, 7, 262144LL, 0, 262144LL, 0, 0, 0, 0, 0, 1.f);

  // T[z=b*8+h] = X1[b] G[h]   [64][1024][512] bf16
  k_gemm8p<1><<<dim3(2, 4, 64), 512, 0, stream>>>(
      in1b, Gt, Tbuf, nullptr, nullptr, nullptr, 512, 512, 512, 512,
      3, 7, SD, 0, 7, 262144LL, 0, SD, 0, 0, 0, 0, 0, 1.f, 0, 0);

  // V-proj transposed: Vt[z][e][s]  [64][512][1024] bf16, +bv
  k_gemm8p<2><<<dim3(2, 4, 64), 512, 0, stream>>>(
      in3b, wvt, Vt, bv, nullptr, nullptr, 512, 512, 512, 1024,
      3, 7, SD, 0, 7, 262144LL, 0, SD, 0, 0, 7, 512, 0, 1.f, 0, 0);

  // attention in 2 chunks of 4 batches (32 heads each)
  for (int c = 0; c < 2; ++c) {
    // scores[zz][i][j] = (T X2^T + rt + ct) * iscale -> bf16
    k_gemm8p<1><<<dim3(4, 4, 32), 512, 0, stream>>>(
        Tbuf + (long long)c * 32 * SD, in2b + (long long)c * 4 * SD, scb, nullptr,
        rt + c * 32768, ct + c * 32768, 512, 512, 512, 1024,
        0, 31, SD, 3, 3, SD, 0, 1048576LL, 0, 0, 0, 0, 1024, iscale, 0, 0);
    k_softmax_bf16<<<8192, 256, 0, stream>>>(scb);
    // heads -> concat[(c*4+b')*1024 + i][h*512 + e]
    k_gemm8p<1><<<dim3(2, 4, 32), 512, 0, stream>>>(
        scb, Vt + (long long)c * 32 * SD, Tbuf + (long long)c * 16777216LL, nullptr,
        nullptr, nullptr, 1024, 1024, 1024, 4096,
        0, 31, 1048576LL, 0, 31, SD, 3, 4194304LL, 7, 512, 0, 0, 0, 1.f, 0, 0);
  }

  // out-proj split-K=4: partials[ks] = concat[:, ks*1024:+1024] @ wot[:, same]^T
  k_gemm8p<0><<<dim3(2, 32, 4), 512, 0, stream>>>(
      Tbuf, wot, partials, nullptr, nullptr, nullptr, 1024, 4096, 4096, 512,
      0, 0, 0, 0, 0, 0, 0, 4194304LL, 0, 0, 0, 0, 0, 1.f, 3, 1024);
  k_reduce4<<<4096, 256, 0, stream>>>(partials, bo, (float*)d_out);
}